// Round 6
// baseline (21961.575 us; speedup 1.0000x reference)
//
#include <hip/hip_runtime.h>

#define BSZ 2048
#define SEQ 50
#define HID 128
#define NHEAD 4
#define HDIM 32
#define INNER 512
#define NITEMS 50000
#define NOUT 49999
#define LROWS 32

__global__ void embed_k(const int* __restrict__ ids, const float* __restrict__ emb,
                        const float* __restrict__ pos, float* __restrict__ x){
  int row = blockIdx.x;          // b*SEQ + l
  int l = row % SEQ;
  int t = threadIdx.x;
  int id = ids[row];
  x[(size_t)row*HID + t] = emb[(size_t)id*HID + t] + pos[l*HID + t];
}

// x_in/x_out bmm with A, concat, @ mixW.T + mixb  (one block per (b,l) row)
__global__ void mix_k(const float* __restrict__ A, const float* __restrict__ xin_,
                      const float* __restrict__ mixW, const float* __restrict__ mixb,
                      float* __restrict__ xout_){
  int row = blockIdx.x; int b = row / SEQ; int t = threadIdx.x;
  __shared__ float Ar[100];
  __shared__ __align__(16) float cat[256];
  if (t < 100) Ar[t] = A[(size_t)row*100 + t];
  __syncthreads();
  float xi = 0.f, xo = 0.f;
  const float* xb = xin_ + (size_t)b*SEQ*HID;
  #pragma unroll 5
  for (int m = 0; m < SEQ; ++m){
    float v = xb[m*HID + t];
    xi += Ar[m]*v;
    xo += Ar[50+m]*v;
  }
  cat[t] = xi; cat[128+t] = xo;
  __syncthreads();
  float acc = mixb[t];
  const float4* w = (const float4*)(mixW + (size_t)t*256);
  const float4* c4 = (const float4*)cat;
  #pragma unroll 8
  for (int j = 0; j < 64; ++j){
    float4 wv = w[j]; float4 cv = c4[j];
    acc += wv.x*cv.x + wv.y*cv.y + wv.z*cv.z + wv.w*cv.w;
  }
  xout_[(size_t)row*HID + t] = acc;
}

// fused qkv + scores + softmax + PV, one block per (b, head)
__global__ void attn_k(const float* __restrict__ x, const float* __restrict__ Wq,
                       const float* __restrict__ bq, const float* __restrict__ Wk,
                       const float* __restrict__ bk, const float* __restrict__ Wv,
                       const float* __restrict__ bv, float* __restrict__ o){
  int blk = blockIdx.x; int b = blk / NHEAD; int h = blk % NHEAD;
  int t = threadIdx.x;
  __shared__ float qs[SEQ][HDIM];
  __shared__ float ks[SEQ][HDIM];
  __shared__ float vs[SEQ][HDIM];
  __shared__ float ss[SEQ][SEQ+2];
  const float* xb = x + (size_t)b*SEQ*HID;
  for (int task = t; task < SEQ*HDIM; task += 256){
    int l = task >> 5, d = task & 31;
    int r = h*HDIM + d;
    const float* xr = xb + l*HID;
    const float* wq = Wq + r*HID;
    const float* wk = Wk + r*HID;
    const float* wv = Wv + r*HID;
    float aq = bq[r], ak = bk[r], av = bv[r];
    #pragma unroll 8
    for (int c = 0; c < HID; ++c){
      float xv = xr[c];
      aq += xv*wq[c]; ak += xv*wk[c]; av += xv*wv[c];
    }
    qs[l][d]=aq; ks[l][d]=ak; vs[l][d]=av;
  }
  __syncthreads();
  for (int task = t; task < SEQ*SEQ; task += 256){
    int l = task / SEQ, m = task % SEQ;
    float a = 0.f;
    #pragma unroll
    for (int d = 0; d < HDIM; ++d) a += qs[l][d]*ks[m][d];
    ss[l][m] = a * 0.17677669529663687f;  // 1/sqrt(32)
  }
  __syncthreads();
  if (t < SEQ){
    float mx = -1e30f;
    for (int m = 0; m < SEQ; ++m) mx = fmaxf(mx, ss[t][m]);
    float sum = 0.f;
    for (int m = 0; m < SEQ; ++m){ float e = __expf(ss[t][m]-mx); ss[t][m]=e; sum+=e; }
    float inv = 1.f/sum;
    for (int m = 0; m < SEQ; ++m) ss[t][m] *= inv;
  }
  __syncthreads();
  for (int task = t; task < SEQ*HDIM; task += 256){
    int l = task >> 5, d = task & 31;
    float a = 0.f;
    for (int m = 0; m < SEQ; ++m) a += ss[l][m]*vs[m][d];
    o[((size_t)b*SEQ+l)*HID + h*HDIM + d] = a;
  }
}

// o @ Wo.T + bo + residual, then LayerNorm. One block (128 thr) per row.
__global__ void oproj_ln_k(const float* __restrict__ o, const float* __restrict__ Wo,
                           const float* __restrict__ bo, const float* __restrict__ g,
                           const float* __restrict__ be, float* __restrict__ x){
  int row = blockIdx.x; int t = threadIdx.x;
  __shared__ __align__(16) float orow[HID];
  __shared__ float red[HID];
  orow[t] = o[(size_t)row*HID + t];
  __syncthreads();
  float acc = bo[t];
  const float4* w = (const float4*)(Wo + (size_t)t*HID);
  const float4* c4 = (const float4*)orow;
  #pragma unroll 8
  for (int j = 0; j < 32; ++j){
    float4 wv = w[j]; float4 cv = c4[j];
    acc += wv.x*cv.x + wv.y*cv.y + wv.z*cv.z + wv.w*cv.w;
  }
  float val = x[(size_t)row*HID + t] + acc;
  red[t] = val; __syncthreads();
  for (int s = 64; s > 0; s >>= 1){ if (t < s) red[t] += red[t+s]; __syncthreads(); }
  float mean = red[0] * (1.f/HID);
  __syncthreads();
  float dv = val - mean;
  red[t] = dv*dv; __syncthreads();
  for (int s = 64; s > 0; s >>= 1){ if (t < s) red[t] += red[t+s]; __syncthreads(); }
  float var = red[0] * (1.f/HID);
  float r = rsqrtf(var + 1e-5f);
  x[(size_t)row*HID + t] = dv * r * g[t] + be[t];
}

// FFN, 32 rows/block, pure fp32 (no bf16 anywhere), linear LDS.
// 256 threads = 32 rows x 8 threads. W1/W2 streamed once per 32 rows.
__global__ __launch_bounds__(256) void ffn32_k(
    const float* __restrict__ x, const float* __restrict__ W1,
    const float* __restrict__ b1, const float* __restrict__ W2,
    const float* __restrict__ b2, const float* __restrict__ gam,
    const float* __restrict__ bet, float* __restrict__ xout)
{
  __shared__ __align__(16) float Xs[32*128];   // 16KB
  __shared__ __align__(16) float Hs[32*512];   // 64KB
  int t = threadIdx.x;
  size_t row0 = (size_t)blockIdx.x * 32;

  // stage X tile fp32 into LDS (4096 floats = 1024 float4 = 4 iters)
  #pragma unroll
  for (int it = 0; it < 4; ++it){
    int idx4 = it*256 + t;
    int r = idx4 >> 5;          // 32 float4-chunks per row
    int c4 = idx4 & 31;
    *(float4*)&Xs[r*128 + c4*4] = *(const float4*)(x + (row0 + r)*HID + c4*4);
  }
  __syncthreads();

  int rt = t >> 3;   // row 0..31
  int ot = t & 7;    // octant: 64 of 512 hidden units
  int nb = ot*64;

  // GEMM1: h[nb..nb+63] = relu(X[rt] @ W1^T + b1)
  float acc[64];
  #pragma unroll
  for (int i = 0; i < 64; ++i) acc[i] = b1[nb + i];
  for (int c8 = 0; c8 < 16; ++c8){
    float4 x0 = *(const float4*)&Xs[rt*128 + c8*8];
    float4 x1 = *(const float4*)&Xs[rt*128 + c8*8 + 4];
    #pragma unroll
    for (int i = 0; i < 64; ++i){
      const float* w1p = W1 + (size_t)(nb + i)*HID + c8*8;
      float4 w0 = *(const float4*)(w1p);
      float4 w1v = *(const float4*)(w1p + 4);
      acc[i] += x0.x*w0.x + x0.y*w0.y + x0.z*w0.z + x0.w*w0.w
              + x1.x*w1v.x + x1.y*w1v.y + x1.z*w1v.z + x1.w*w1v.w;
    }
  }
  #pragma unroll
  for (int i = 0; i < 64; ++i){
    Hs[rt*512 + nb + i] = fmaxf(acc[i], 0.f);
  }
  __syncthreads();

  // GEMM2: ff[ot*16 .. +15] = H[rt] @ W2^T + b2, + residual, LN
  size_t grow = row0 + (size_t)rt;
  const float* xr = x + grow*HID;
  float vals[16];
  #pragma unroll
  for (int i = 0; i < 16; ++i) vals[i] = b2[ot*16 + i];

  for (int c = 0; c < 64; ++c){
    float4 h0 = *(const float4*)&Hs[rt*512 + c*8];
    float4 h1 = *(const float4*)&Hs[rt*512 + c*8 + 4];
    #pragma unroll
    for (int i = 0; i < 16; ++i){
      const float* w2p = W2 + (size_t)(ot*16 + i)*INNER + c*8;
      float4 w0 = *(const float4*)(w2p);
      float4 w1v = *(const float4*)(w2p + 4);
      vals[i] += h0.x*w0.x + h0.y*w0.y + h0.z*w0.z + h0.w*w0.w
               + h1.x*w1v.x + h1.y*w1v.y + h1.z*w1v.z + h1.w*w1v.w;
    }
  }

  float s = 0.f;
  #pragma unroll
  for (int i = 0; i < 16; ++i){
    vals[i] += xr[ot*16 + i];       // residual
    s += vals[i];
  }
  s += __shfl_xor(s, 1, 64);
  s += __shfl_xor(s, 2, 64);
  s += __shfl_xor(s, 4, 64);
  float mean = s * (1.f/HID);
  float qv = 0.f;
  #pragma unroll
  for (int i = 0; i < 16; ++i){ float d = vals[i]-mean; qv += d*d; }
  qv += __shfl_xor(qv, 1, 64);
  qv += __shfl_xor(qv, 2, 64);
  qv += __shfl_xor(qv, 4, 64);
  float rstd = rsqrtf(qv*(1.f/HID) + 1e-5f);
  float* orow = xout + grow*HID;
  #pragma unroll
  for (int i = 0; i < 16; ++i){
    int n = ot*16 + i;
    orow[n] = (vals[i]-mean)*rstd*gam[n] + bet[n];
  }
}

// attention pooling + session vector. One block (128 thr) per batch elem.
__global__ void final_k(const float* __restrict__ x, const float* __restrict__ attW,
                        const float* __restrict__ attb, const float* __restrict__ sessW,
                        const float* __restrict__ sessb, float* __restrict__ sess){
  int b = blockIdx.x; int t = threadIdx.x;
  __shared__ float av[SEQ];
  __shared__ __align__(16) float cat[256];
  const float* xb = x + (size_t)b*SEQ*HID;
  if (t < SEQ){
    float a = attb[0];
    for (int c = 0; c < HID; ++c) a += xb[t*HID + c]*attW[c];
    av[t] = a;
  }
  __syncthreads();
  if (t == 0){
    float s = 0.f;
    for (int l = 0; l < SEQ; ++l) s += av[l];
    float inv = 1.f/s;
    for (int l = 0; l < SEQ; ++l) av[l] *= inv;
  }
  __syncthreads();
  float gacc = 0.f;
  for (int l = 0; l < SEQ; ++l) gacc += xb[l*HID + t]*av[l];
  cat[t] = xb[49*HID + t];
  cat[128+t] = gacc;
  __syncthreads();
  float acc = sessb[t];
  const float4* w = (const float4*)(sessW + (size_t)t*256);
  const float4* c4 = (const float4*)cat;
  #pragma unroll 8
  for (int j = 0; j < 64; ++j){
    float4 wv=w[j]; float4 cv=c4[j];
    acc += wv.x*cv.x + wv.y*cv.y + wv.z*cv.z + wv.w*cv.w;
  }
  sess[(size_t)b*HID + t] = acc;
}

// logits = sess @ emb[1:].T   (2048 x 49999, K=128)
__global__ void logits_k(const float* __restrict__ sess, const float* __restrict__ emb,
                         float* __restrict__ out){
  int t = threadIdx.x;
  int n0 = blockIdx.x * 256;
  int r0 = blockIdx.y * LROWS;
  __shared__ __align__(16) float ss[LROWS][HID];
  float* ssf = (float*)ss;
  for (int i = t; i < LROWS*HID; i += 256) ssf[i] = sess[(size_t)r0*HID + i];
  __syncthreads();
  int n = n0 + t;
  if (n >= NOUT) return;
  const float4* er = (const float4*)(emb + (size_t)(1+n)*HID);
  float acc[LROWS];
  #pragma unroll
  for (int r = 0; r < LROWS; ++r) acc[r] = 0.f;
  for (int c4i = 0; c4i < 32; ++c4i){
    float4 e = er[c4i];
    int c = c4i*4;
    #pragma unroll
    for (int r = 0; r < LROWS; ++r){
      acc[r] += e.x*ss[r][c] + e.y*ss[r][c+1] + e.z*ss[r][c+2] + e.w*ss[r][c+3];
    }
  }
  #pragma unroll
  for (int r = 0; r < LROWS; ++r){
    out[(size_t)(r0+r)*NOUT + n] = acc[r];
  }
}

extern "C" void kernel_launch(void* const* d_in, const int* in_sizes, int n_in,
                              void* d_out, int out_size, void* d_ws, size_t ws_size,
                              hipStream_t stream){
  const int*   ids  = (const int*)d_in[0];
  const float* A    = (const float*)d_in[1];
  const float* emb  = (const float*)d_in[2];
  const float* pos  = (const float*)d_in[3];
  const float* mixW = (const float*)d_in[4];
  const float* mixb = (const float*)d_in[5];
  const float* Wq   = (const float*)d_in[6];
  const float* bq   = (const float*)d_in[7];
  const float* Wk   = (const float*)d_in[8];
  const float* bk   = (const float*)d_in[9];
  const float* Wv   = (const float*)d_in[10];
  const float* bv   = (const float*)d_in[11];
  const float* Wo   = (const float*)d_in[12];
  const float* bo   = (const float*)d_in[13];
  const float* ln1g = (const float*)d_in[14];
  const float* ln1b = (const float*)d_in[15];
  const float* W1   = (const float*)d_in[16];
  const float* b1   = (const float*)d_in[17];
  const float* W2   = (const float*)d_in[18];
  const float* b2   = (const float*)d_in[19];
  const float* ln2g = (const float*)d_in[20];
  const float* ln2b = (const float*)d_in[21];
  const float* attW = (const float*)d_in[22];
  const float* attb = (const float*)d_in[23];
  const float* sessW= (const float*)d_in[24];
  const float* sessb= (const float*)d_in[25];
  float* out = (float*)d_out;

  float* xA   = (float*)d_ws;
  float* xB   = xA + (size_t)BSZ*SEQ*HID;
  float* sess = xB + (size_t)BSZ*SEQ*HID;

  embed_k<<<BSZ*SEQ, HID, 0, stream>>>(ids, emb, pos, xA);
  float* xc = xA; float* xn = xB;
  for (int i = 0; i < 2; ++i){
    mix_k<<<BSZ*SEQ, HID, 0, stream>>>(A, xc, mixW + (size_t)i*HID*2*HID, mixb + i*HID, xn);
    attn_k<<<BSZ*NHEAD, 256, 0, stream>>>(xn, Wq + (size_t)i*HID*HID, bq + i*HID,
                                          Wk + (size_t)i*HID*HID, bk + i*HID,
                                          Wv + (size_t)i*HID*HID, bv + i*HID, xc);
    oproj_ln_k<<<BSZ*SEQ, HID, 0, stream>>>(xc, Wo + (size_t)i*HID*HID, bo + i*HID,
                                            ln1g + i*HID, ln1b + i*HID, xn);
    ffn32_k<<<BSZ*SEQ/32, 256, 0, stream>>>(xn, W1 + (size_t)i*INNER*HID, b1 + i*INNER,
                                            W2 + (size_t)i*HID*INNER, b2 + i*HID,
                                            ln2g + i*HID, ln2b + i*HID, xn);
    float* tmp = xc; xc = xn; xn = tmp;
  }
  final_k<<<BSZ, HID, 0, stream>>>(xc, attW, attb, sessW, sessb, sess);
  dim3 lgrid((NOUT + 255)/256, BSZ/LROWS);
  logits_k<<<lgrid, 256, 0, stream>>>(sess, emb, out);
}

// Round 7
// 11076.328 us; speedup vs baseline: 1.9827x; 1.9827x over previous
//
#include <hip/hip_runtime.h>

#define BSZ 2048
#define SEQ 50
#define HID 128
#define NHEAD 4
#define HDIM 32
#define INNER 512
#define NITEMS 50000
#define NOUT 49999
#define LROWS 32

typedef float f32x4 __attribute__((ext_vector_type(4)));
typedef short s16x8 __attribute__((ext_vector_type(8)));

__device__ __forceinline__ unsigned short f2b(float f){
  unsigned int u = __builtin_bit_cast(unsigned int, f);
  u = (u + 0x7FFFu + ((u >> 16) & 1u)) >> 16;
  return (unsigned short)u;
}
__device__ __forceinline__ float b2f(unsigned short h){
  unsigned int u = ((unsigned int)h) << 16;
  return __builtin_bit_cast(float, u);
}

__global__ void embed_k(const int* __restrict__ ids, const float* __restrict__ emb,
                        const float* __restrict__ pos, float* __restrict__ x){
  int row = blockIdx.x;          // b*SEQ + l
  int l = row % SEQ;
  int t = threadIdx.x;
  int id = ids[row];
  x[(size_t)row*HID + t] = emb[(size_t)id*HID + t] + pos[l*HID + t];
}

// split W1/W2 into bf16 hi/lo pairs (both layers)
__global__ void cvtw2_k(const float* __restrict__ W1, const float* __restrict__ W2,
                        unsigned short* __restrict__ W1h, unsigned short* __restrict__ W1l,
                        unsigned short* __restrict__ W2h, unsigned short* __restrict__ W2l){
  int i = blockIdx.x*256 + threadIdx.x;   // 2*512*128 = 131072 each
  float w1 = W1[i];
  unsigned short h1 = f2b(w1);
  W1h[i] = h1; W1l[i] = f2b(w1 - b2f(h1));
  float w2 = W2[i];
  unsigned short h2 = f2b(w2);
  W2h[i] = h2; W2l[i] = f2b(w2 - b2f(h2));
}

// x_in/x_out bmm with A, concat, @ mixW.T + mixb  (one block per (b,l) row)
__global__ void mix_k(const float* __restrict__ A, const float* __restrict__ xin_,
                      const float* __restrict__ mixW, const float* __restrict__ mixb,
                      float* __restrict__ xout_){
  int row = blockIdx.x; int b = row / SEQ; int t = threadIdx.x;
  __shared__ float Ar[100];
  __shared__ __align__(16) float cat[256];
  if (t < 100) Ar[t] = A[(size_t)row*100 + t];
  __syncthreads();
  float xi = 0.f, xo = 0.f;
  const float* xb = xin_ + (size_t)b*SEQ*HID;
  #pragma unroll 5
  for (int m = 0; m < SEQ; ++m){
    float v = xb[m*HID + t];
    xi += Ar[m]*v;
    xo += Ar[50+m]*v;
  }
  cat[t] = xi; cat[128+t] = xo;
  __syncthreads();
  float acc = mixb[t];
  const float4* w = (const float4*)(mixW + (size_t)t*256);
  const float4* c4 = (const float4*)cat;
  #pragma unroll 8
  for (int j = 0; j < 64; ++j){
    float4 wv = w[j]; float4 cv = c4[j];
    acc += wv.x*cv.x + wv.y*cv.y + wv.z*cv.z + wv.w*cv.w;
  }
  xout_[(size_t)row*HID + t] = acc;
}

// fused qkv + scores + softmax + PV, one block per (b, head)
__global__ void attn_k(const float* __restrict__ x, const float* __restrict__ Wq,
                       const float* __restrict__ bq, const float* __restrict__ Wk,
                       const float* __restrict__ bk, const float* __restrict__ Wv,
                       const float* __restrict__ bv, float* __restrict__ o){
  int blk = blockIdx.x; int b = blk / NHEAD; int h = blk % NHEAD;
  int t = threadIdx.x;
  __shared__ float qs[SEQ][HDIM];
  __shared__ float ks[SEQ][HDIM];
  __shared__ float vs[SEQ][HDIM];
  __shared__ float ss[SEQ][SEQ+2];
  const float* xb = x + (size_t)b*SEQ*HID;
  for (int task = t; task < SEQ*HDIM; task += 256){
    int l = task >> 5, d = task & 31;
    int r = h*HDIM + d;
    const float* xr = xb + l*HID;
    const float* wq = Wq + r*HID;
    const float* wk = Wk + r*HID;
    const float* wv = Wv + r*HID;
    float aq = bq[r], ak = bk[r], av = bv[r];
    #pragma unroll 8
    for (int c = 0; c < HID; ++c){
      float xv = xr[c];
      aq += xv*wq[c]; ak += xv*wk[c]; av += xv*wv[c];
    }
    qs[l][d]=aq; ks[l][d]=ak; vs[l][d]=av;
  }
  __syncthreads();
  for (int task = t; task < SEQ*SEQ; task += 256){
    int l = task / SEQ, m = task % SEQ;
    float a = 0.f;
    #pragma unroll
    for (int d = 0; d < HDIM; ++d) a += qs[l][d]*ks[m][d];
    ss[l][m] = a * 0.17677669529663687f;  // 1/sqrt(32)
  }
  __syncthreads();
  if (t < SEQ){
    float mx = -1e30f;
    for (int m = 0; m < SEQ; ++m) mx = fmaxf(mx, ss[t][m]);
    float sum = 0.f;
    for (int m = 0; m < SEQ; ++m){ float e = __expf(ss[t][m]-mx); ss[t][m]=e; sum+=e; }
    float inv = 1.f/sum;
    for (int m = 0; m < SEQ; ++m) ss[t][m] *= inv;
  }
  __syncthreads();
  for (int task = t; task < SEQ*HDIM; task += 256){
    int l = task >> 5, d = task & 31;
    float a = 0.f;
    for (int m = 0; m < SEQ; ++m) a += ss[l][m]*vs[m][d];
    o[((size_t)b*SEQ+l)*HID + h*HDIM + d] = a;
  }
}

// o @ Wo.T + bo + residual, then LayerNorm. One block (128 thr) per row.
__global__ void oproj_ln_k(const float* __restrict__ o, const float* __restrict__ Wo,
                           const float* __restrict__ bo, const float* __restrict__ g,
                           const float* __restrict__ be, float* __restrict__ x){
  int row = blockIdx.x; int t = threadIdx.x;
  __shared__ __align__(16) float orow[HID];
  __shared__ float red[HID];
  orow[t] = o[(size_t)row*HID + t];
  __syncthreads();
  float acc = bo[t];
  const float4* w = (const float4*)(Wo + (size_t)t*HID);
  const float4* c4 = (const float4*)orow;
  #pragma unroll 8
  for (int j = 0; j < 32; ++j){
    float4 wv = w[j]; float4 cv = c4[j];
    acc += wv.x*cv.x + wv.y*cv.y + wv.z*cv.z + wv.w*cv.w;
  }
  float val = x[(size_t)row*HID + t] + acc;
  red[t] = val; __syncthreads();
  for (int s = 64; s > 0; s >>= 1){ if (t < s) red[t] += red[t+s]; __syncthreads(); }
  float mean = red[0] * (1.f/HID);
  __syncthreads();
  float dv = val - mean;
  red[t] = dv*dv; __syncthreads();
  for (int s = 64; s > 0; s >>= 1){ if (t < s) red[t] += red[t+s]; __syncthreads(); }
  float var = red[0] * (1.f/HID);
  float r = rsqrtf(var + 1e-5f);
  x[(size_t)row*HID + t] = dv * r * g[t] + be[t];
}

// FFN via split-bf16 MFMA (hi/lo, 3-term): fp32-accurate.
// 32 rows/block, 4 waves: wave = (row_half, n_half). Swizzled LDS (R2 scheme).
__global__ __launch_bounds__(256) void ffn_mfma2_k(
    const float* __restrict__ x,
    const unsigned short* __restrict__ W1h, const unsigned short* __restrict__ W1l,
    const float* __restrict__ b1,
    const unsigned short* __restrict__ W2h, const unsigned short* __restrict__ W2l,
    const float* __restrict__ b2, const float* __restrict__ gam,
    const float* __restrict__ bet, float* __restrict__ xout)
{
  __shared__ unsigned short Xh[32*128];   // 8KB swizzled rows of 256B
  __shared__ unsigned short Xl[32*128];   // 8KB
  __shared__ unsigned short Hh[32*512];   // 32KB swizzled rows of 1024B
  __shared__ unsigned short Hl[32*512];   // 32KB
  __shared__ float red_s[2][2][16];
  __shared__ float red_q[2][2][16];
  int t = threadIdx.x;
  int wave = t >> 6, lane = t & 63;
  int g = lane >> 4, c16 = lane & 15;
  int wrh = wave >> 1;   // row half: rows wrh*16 .. +15
  int wn  = wave & 1;    // n/j half
  size_t row0 = (size_t)blockIdx.x * 32;

  // stage X tile fp32 -> bf16 hi/lo into swizzled LDS
  #pragma unroll
  for (int it = 0; it < 2; ++it){
    int idx8 = it*256 + t;          // 512 chunks of 8 elems
    int r = idx8 >> 4;              // 16 chunks per row
    int c8 = idx8 & 15;
    const float* src = x + (row0 + r)*HID + c8*8;
    float4 v0 = *(const float4*)(src);
    float4 v1 = *(const float4*)(src + 4);
    float f[8] = {v0.x,v0.y,v0.z,v0.w,v1.x,v1.y,v1.z,v1.w};
    s16x8 ph, pl;
    #pragma unroll
    for (int e = 0; e < 8; ++e){
      unsigned short hi = f2b(f[e]);
      ph[e] = (short)hi;
      pl[e] = (short)f2b(f[e] - b2f(hi));
    }
    int slot = c8 ^ (r & 15);
    *(s16x8*)((char*)Xh + r*256 + slot*16) = ph;
    *(s16x8*)((char*)Xl + r*256 + slot*16) = pl;
  }
  __syncthreads();

  // A-frags for this wave's 16 rows (row = wrh*16 + c16, k = kt*32 + g*8 + j)
  int rloc = wrh*16 + c16;
  s16x8 afh[4], afl[4];
  #pragma unroll
  for (int kt = 0; kt < 4; ++kt){
    int slot = (kt*4 + g) ^ (rloc & 15);
    afh[kt] = *(const s16x8*)((const char*)Xh + rloc*256 + slot*16);
    afl[kt] = *(const s16x8*)((const char*)Xl + rloc*256 + slot*16);
  }

  // GEMM1: H = relu(X @ W1^T + b1), 3-term split -> swizzled hi/lo LDS
  for (int nt = 0; nt < 16; ++nt){
    int ntg = wn*16 + nt;
    int nrow = ntg*16 + c16;
    const unsigned short* wrh_p = W1h + nrow*HID + g*8;
    const unsigned short* wrl_p = W1l + nrow*HID + g*8;
    f32x4 acc = {0.f,0.f,0.f,0.f};
    #pragma unroll
    for (int kt = 0; kt < 4; ++kt){
      s16x8 bh = *(const s16x8*)(wrh_p + kt*32);
      s16x8 bl = *(const s16x8*)(wrl_p + kt*32);
      acc = __builtin_amdgcn_mfma_f32_16x16x32_bf16(afh[kt], bh, acc, 0,0,0);
      acc = __builtin_amdgcn_mfma_f32_16x16x32_bf16(afh[kt], bl, acc, 0,0,0);
      acc = __builtin_amdgcn_mfma_f32_16x16x32_bf16(afl[kt], bh, acc, 0,0,0);
    }
    float bv = b1[nrow];
    #pragma unroll
    for (int r = 0; r < 4; ++r){
      int m = wrh*16 + g*4 + r;        // D: row=(lane>>4)*4+reg, col=lane&15
      float h = fmaxf(acc[r] + bv, 0.f);
      unsigned short hh = f2b(h);
      unsigned short hl = f2b(h - b2f(hh));
      int colb = nrow*2;
      int byteoff = m*1024 + (((((colb>>4) ^ (m & 15))<<4)) | (colb & 15));
      *(unsigned short*)((char*)Hh + byteoff) = hh;
      *(unsigned short*)((char*)Hl + byteoff) = hl;
    }
  }
  __syncthreads();

  // GEMM2 as O^T = W2 * H^T (A=W2 rows j, B-frag = H rows m), 3-term split
  f32x4 acc2[4];
  #pragma unroll
  for (int i = 0; i < 4; ++i) acc2[i] = (f32x4){0.f,0.f,0.f,0.f};
  int hrow = wrh*16 + c16;
  for (int kt2 = 0; kt2 < 16; ++kt2){
    int slot = (kt2*4 + g) ^ (hrow & 15);
    s16x8 hfh = *(const s16x8*)((const char*)Hh + hrow*1024 + slot*16);
    s16x8 hfl = *(const s16x8*)((const char*)Hl + hrow*1024 + slot*16);
    #pragma unroll
    for (int nt2 = 0; nt2 < 4; ++nt2){
      int jrow = (wn*4 + nt2)*16 + c16;
      s16x8 wfh = *(const s16x8*)(W2h + (size_t)jrow*INNER + kt2*32 + g*8);
      s16x8 wfl = *(const s16x8*)(W2l + (size_t)jrow*INNER + kt2*32 + g*8);
      acc2[nt2] = __builtin_amdgcn_mfma_f32_16x16x32_bf16(wfh, hfh, acc2[nt2], 0,0,0);
      acc2[nt2] = __builtin_amdgcn_mfma_f32_16x16x32_bf16(wfh, hfl, acc2[nt2], 0,0,0);
      acc2[nt2] = __builtin_amdgcn_mfma_f32_16x16x32_bf16(wfl, hfh, acc2[nt2], 0,0,0);
    }
  }

  // epilogue: lane holds O[row m = hrow][j = (wn*4+nt2)*16 + g*4 + r]
  size_t grow = row0 + (size_t)hrow;
  const float* xr = x + grow*HID;
  float vals[16];
  float s = 0.f, q = 0.f;
  #pragma unroll
  for (int nt2 = 0; nt2 < 4; ++nt2){
    #pragma unroll
    for (int r = 0; r < 4; ++r){
      int j = (wn*4 + nt2)*16 + g*4 + r;
      float v = acc2[nt2][r] + b2[j] + xr[j];
      vals[nt2*4+r] = v;
      s += v; q += v*v;
    }
  }
  s += __shfl_xor(s, 16, 64);
  s += __shfl_xor(s, 32, 64);
  q += __shfl_xor(q, 16, 64);
  q += __shfl_xor(q, 32, 64);
  if (g == 0){
    red_s[wrh][wn][c16] = s;
    red_q[wrh][wn][c16] = q;
  }
  __syncthreads();
  float s_tot = red_s[wrh][0][c16] + red_s[wrh][1][c16];
  float q_tot = red_q[wrh][0][c16] + red_q[wrh][1][c16];
  float mean = s_tot * (1.f/HID);
  float var = q_tot * (1.f/HID) - mean*mean;
  float rstd = rsqrtf(var + 1e-5f);
  float* orow = xout + grow*HID;
  #pragma unroll
  for (int nt2 = 0; nt2 < 4; ++nt2){
    #pragma unroll
    for (int r = 0; r < 4; ++r){
      int j = (wn*4 + nt2)*16 + g*4 + r;
      orow[j] = (vals[nt2*4+r]-mean)*rstd*gam[j] + bet[j];
    }
  }
}

// attention pooling + session vector. One block (128 thr) per batch elem.
__global__ void final_k(const float* __restrict__ x, const float* __restrict__ attW,
                        const float* __restrict__ attb, const float* __restrict__ sessW,
                        const float* __restrict__ sessb, float* __restrict__ sess){
  int b = blockIdx.x; int t = threadIdx.x;
  __shared__ float av[SEQ];
  __shared__ __align__(16) float cat[256];
  const float* xb = x + (size_t)b*SEQ*HID;
  if (t < SEQ){
    float a = attb[0];
    for (int c = 0; c < HID; ++c) a += xb[t*HID + c]*attW[c];
    av[t] = a;
  }
  __syncthreads();
  if (t == 0){
    float s = 0.f;
    for (int l = 0; l < SEQ; ++l) s += av[l];
    float inv = 1.f/s;
    for (int l = 0; l < SEQ; ++l) av[l] *= inv;
  }
  __syncthreads();
  float gacc = 0.f;
  for (int l = 0; l < SEQ; ++l) gacc += xb[l*HID + t]*av[l];
  cat[t] = xb[49*HID + t];
  cat[128+t] = gacc;
  __syncthreads();
  float acc = sessb[t];
  const float4* w = (const float4*)(sessW + (size_t)t*256);
  const float4* c4 = (const float4*)cat;
  #pragma unroll 8
  for (int j = 0; j < 64; ++j){
    float4 wv=w[j]; float4 cv=c4[j];
    acc += wv.x*cv.x + wv.y*cv.y + wv.z*cv.z + wv.w*cv.w;
  }
  sess[(size_t)b*HID + t] = acc;
}

// logits = sess @ emb[1:].T   (2048 x 49999, K=128)
__global__ void logits_k(const float* __restrict__ sess, const float* __restrict__ emb,
                         float* __restrict__ out){
  int t = threadIdx.x;
  int n0 = blockIdx.x * 256;
  int r0 = blockIdx.y * LROWS;
  __shared__ __align__(16) float ss[LROWS][HID];
  float* ssf = (float*)ss;
  for (int i = t; i < LROWS*HID; i += 256) ssf[i] = sess[(size_t)r0*HID + i];
  __syncthreads();
  int n = n0 + t;
  if (n >= NOUT) return;
  const float4* er = (const float4*)(emb + (size_t)(1+n)*HID);
  float acc[LROWS];
  #pragma unroll
  for (int r = 0; r < LROWS; ++r) acc[r] = 0.f;
  for (int c4i = 0; c4i < 32; ++c4i){
    float4 e = er[c4i];
    int c = c4i*4;
    #pragma unroll
    for (int r = 0; r < LROWS; ++r){
      acc[r] += e.x*ss[r][c] + e.y*ss[r][c+1] + e.z*ss[r][c+2] + e.w*ss[r][c+3];
    }
  }
  #pragma unroll
  for (int r = 0; r < LROWS; ++r){
    out[(size_t)(r0+r)*NOUT + n] = acc[r];
  }
}

extern "C" void kernel_launch(void* const* d_in, const int* in_sizes, int n_in,
                              void* d_out, int out_size, void* d_ws, size_t ws_size,
                              hipStream_t stream){
  const int*   ids  = (const int*)d_in[0];
  const float* A    = (const float*)d_in[1];
  const float* emb  = (const float*)d_in[2];
  const float* pos  = (const float*)d_in[3];
  const float* mixW = (const float*)d_in[4];
  const float* mixb = (const float*)d_in[5];
  const float* Wq   = (const float*)d_in[6];
  const float* bq   = (const float*)d_in[7];
  const float* Wk   = (const float*)d_in[8];
  const float* bk   = (const float*)d_in[9];
  const float* Wv   = (const float*)d_in[10];
  const float* bv   = (const float*)d_in[11];
  const float* Wo   = (const float*)d_in[12];
  const float* bo   = (const float*)d_in[13];
  const float* ln1g = (const float*)d_in[14];
  const float* ln1b = (const float*)d_in[15];
  const float* W1   = (const float*)d_in[16];
  const float* b1   = (const float*)d_in[17];
  const float* W2   = (const float*)d_in[18];
  const float* b2   = (const float*)d_in[19];
  const float* ln2g = (const float*)d_in[20];
  const float* ln2b = (const float*)d_in[21];
  const float* attW = (const float*)d_in[22];
  const float* attb = (const float*)d_in[23];
  const float* sessW= (const float*)d_in[24];
  const float* sessb= (const float*)d_in[25];
  float* out = (float*)d_out;

  float* xA   = (float*)d_ws;
  float* xB   = xA + (size_t)BSZ*SEQ*HID;
  float* sess = xB + (size_t)BSZ*SEQ*HID;
  // W hi/lo splits live inside the sess region (exactly 1MB = 4 x 256KB).
  // sess is only written by final_k, after the last FFN -> no conflict.
  unsigned short* W1h = (unsigned short*)sess;
  unsigned short* W1l = W1h + (size_t)2*INNER*HID;
  unsigned short* W2h = W1l + (size_t)2*INNER*HID;
  unsigned short* W2l = W2h + (size_t)2*INNER*HID;

  cvtw2_k<<<512, 256, 0, stream>>>(W1, W2, W1h, W1l, W2h, W2l);
  embed_k<<<BSZ*SEQ, HID, 0, stream>>>(ids, emb, pos, xA);
  float* xc = xA; float* xn = xB;
  for (int i = 0; i < 2; ++i){
    mix_k<<<BSZ*SEQ, HID, 0, stream>>>(A, xc, mixW + (size_t)i*HID*2*HID, mixb + i*HID, xn);
    attn_k<<<BSZ*NHEAD, 256, 0, stream>>>(xn, Wq + (size_t)i*HID*HID, bq + i*HID,
                                          Wk + (size_t)i*HID*HID, bk + i*HID,
                                          Wv + (size_t)i*HID*HID, bv + i*HID, xc);
    oproj_ln_k<<<BSZ*SEQ, HID, 0, stream>>>(xc, Wo + (size_t)i*HID*HID, bo + i*HID,
                                            ln1g + i*HID, ln1b + i*HID, xn);
    ffn_mfma2_k<<<BSZ*SEQ/32, 256, 0, stream>>>(xn,
        W1h + (size_t)i*INNER*HID, W1l + (size_t)i*INNER*HID, b1 + i*INNER,
        W2h + (size_t)i*INNER*HID, W2l + (size_t)i*INNER*HID, b2 + i*HID,
        ln2g + i*HID, ln2b + i*HID, xn);
    float* tmp = xc; xc = xn; xn = tmp;
  }
  final_k<<<BSZ, HID, 0, stream>>>(xc, attW, attb, sessW, sessb, sess);
  dim3 lgrid((NOUT + 255)/256, BSZ/LROWS);
  logits_k<<<lgrid, 256, 0, stream>>>(sess, emb, out);
}

// Round 10
// 5996.885 us; speedup vs baseline: 3.6622x; 1.8470x over previous
//
#include <hip/hip_runtime.h>

#define BSZ 2048
#define SEQ 50
#define HID 128
#define NHEAD 4
#define HDIM 32
#define INNER 512
#define NITEMS 50000
#define NOUT 49999
#define LROWS 32

typedef float f32x4 __attribute__((ext_vector_type(4)));
typedef short s16x8 __attribute__((ext_vector_type(8)));

__device__ __forceinline__ unsigned short f2b(float f){
  unsigned int u = __builtin_bit_cast(unsigned int, f);
  u = (u + 0x7FFFu + ((u >> 16) & 1u)) >> 16;
  return (unsigned short)u;
}
__device__ __forceinline__ float b2f(unsigned short h){
  unsigned int u = ((unsigned int)h) << 16;
  return __builtin_bit_cast(float, u);
}

__global__ void embed_k(const int* __restrict__ ids, const float* __restrict__ emb,
                        const float* __restrict__ pos, float* __restrict__ x){
  int row = blockIdx.x;          // b*SEQ + l
  int l = row % SEQ;
  int t = threadIdx.x;
  int id = ids[row];
  x[(size_t)row*HID + t] = emb[(size_t)id*HID + t] + pos[l*HID + t];
}

// split W1/W2 into bf16 hi/lo pairs (both layers)
__global__ void cvtw2_k(const float* __restrict__ W1, const float* __restrict__ W2,
                        unsigned short* __restrict__ W1h, unsigned short* __restrict__ W1l,
                        unsigned short* __restrict__ W2h, unsigned short* __restrict__ W2l){
  int i = blockIdx.x*256 + threadIdx.x;   // 2*512*128 = 131072 each
  float w1 = W1[i];
  unsigned short h1 = f2b(w1);
  W1h[i] = h1; W1l[i] = f2b(w1 - b2f(h1));
  float w2 = W2[i];
  unsigned short h2 = f2b(w2);
  W2h[i] = h2; W2l[i] = f2b(w2 - b2f(h2));
}

// Wq/Wk/Wv stacked into [2][384][128] hi/lo; Wo into [2][128][128] hi/lo.
__global__ void cvtw_qkvo_k(const float* __restrict__ Wq, const float* __restrict__ Wk,
                            const float* __restrict__ Wv, const float* __restrict__ Wo,
                            unsigned short* __restrict__ dst){
  int i = blockIdx.x*256 + threadIdx.x;   // 0..32767 (2 layers x 128 x 128)
  int l = i >> 14;
  int rc = i & 16383;
  unsigned short* Wqkvh = dst;                 // 98304 ushorts
  unsigned short* Wqkvl = dst + 98304;
  unsigned short* Woh   = dst + 196608;        // 32768
  unsigned short* Wol   = dst + 229376;
  size_t base = (size_t)l*384*128;
  float w; unsigned short h;
  w = Wq[i]; h = f2b(w); Wqkvh[base + rc]         = h; Wqkvl[base + rc]         = f2b(w - b2f(h));
  w = Wk[i]; h = f2b(w); Wqkvh[base + 16384 + rc] = h; Wqkvl[base + 16384 + rc] = f2b(w - b2f(h));
  w = Wv[i]; h = f2b(w); Wqkvh[base + 32768 + rc] = h; Wqkvl[base + 32768 + rc] = f2b(w - b2f(h));
  w = Wo[i]; h = f2b(w); Woh[i] = h; Wol[i] = f2b(w - b2f(h));
}

// x_in/x_out bmm with A, concat, @ mixW.T + mixb  (one block per (b,l) row)
__global__ void mix_k(const float* __restrict__ A, const float* __restrict__ xin_,
                      const float* __restrict__ mixW, const float* __restrict__ mixb,
                      float* __restrict__ xout_){
  int row = blockIdx.x; int b = row / SEQ; int t = threadIdx.x;
  __shared__ float Ar[100];
  __shared__ __align__(16) float cat[256];
  if (t < 100) Ar[t] = A[(size_t)row*100 + t];
  __syncthreads();
  float xi = 0.f, xo = 0.f;
  const float* xb = xin_ + (size_t)b*SEQ*HID;
  #pragma unroll 5
  for (int m = 0; m < SEQ; ++m){
    float v = xb[m*HID + t];
    xi += Ar[m]*v;
    xo += Ar[50+m]*v;
  }
  cat[t] = xi; cat[128+t] = xo;
  __syncthreads();
  float acc = mixb[t];
  const float4* w = (const float4*)(mixW + (size_t)t*256);
  const float4* c4 = (const float4*)cat;
  #pragma unroll 8
  for (int j = 0; j < 64; ++j){
    float4 wv = w[j]; float4 cv = c4[j];
    acc += wv.x*cv.x + wv.y*cv.y + wv.z*cv.z + wv.w*cv.w;
  }
  xout_[(size_t)row*HID + t] = acc;
}

// QKV projection: clone of ffn_mfma2_k GEMM1. 32 rows/block, 4 waves
// (wave = row_half x n_half), 12 n-tiles per n-half (384 cols = Wq|Wk|Wv).
// Output fp32 qkv[row][384].
__global__ __launch_bounds__(256) void qkv_mfma_k(
    const float* __restrict__ x,
    const unsigned short* __restrict__ Wh, const unsigned short* __restrict__ Wl,
    const float* __restrict__ bq, const float* __restrict__ bk,
    const float* __restrict__ bv, float* __restrict__ qkv)
{
  __shared__ unsigned short Xh[32*128];
  __shared__ unsigned short Xl[32*128];
  int t = threadIdx.x;
  int wave = t >> 6, lane = t & 63;
  int g = lane >> 4, c16 = lane & 15;
  int wrh = wave >> 1;
  int wn  = wave & 1;
  size_t row0 = (size_t)blockIdx.x * 32;

  #pragma unroll
  for (int it = 0; it < 2; ++it){
    int idx8 = it*256 + t;
    int r = idx8 >> 4;
    int c8 = idx8 & 15;
    const float* src = x + (row0 + r)*HID + c8*8;
    float4 v0 = *(const float4*)(src);
    float4 v1 = *(const float4*)(src + 4);
    float f[8] = {v0.x,v0.y,v0.z,v0.w,v1.x,v1.y,v1.z,v1.w};
    s16x8 ph, pl;
    #pragma unroll
    for (int e = 0; e < 8; ++e){
      unsigned short hi = f2b(f[e]);
      ph[e] = (short)hi;
      pl[e] = (short)f2b(f[e] - b2f(hi));
    }
    int slot = c8 ^ (r & 15);
    *(s16x8*)((char*)Xh + r*256 + slot*16) = ph;
    *(s16x8*)((char*)Xl + r*256 + slot*16) = pl;
  }
  __syncthreads();

  int rloc = wrh*16 + c16;
  s16x8 afh[4], afl[4];
  #pragma unroll
  for (int kt = 0; kt < 4; ++kt){
    int slot = (kt*4 + g) ^ (rloc & 15);
    afh[kt] = *(const s16x8*)((const char*)Xh + rloc*256 + slot*16);
    afl[kt] = *(const s16x8*)((const char*)Xl + rloc*256 + slot*16);
  }

  for (int nt = 0; nt < 12; ++nt){
    int tile = wn*12 + nt;
    int ncol = tile*16 + c16;          // 0..383
    const unsigned short* wrh_p = Wh + (size_t)ncol*HID + g*8;
    const unsigned short* wrl_p = Wl + (size_t)ncol*HID + g*8;
    f32x4 acc = {0.f,0.f,0.f,0.f};
    #pragma unroll
    for (int kt = 0; kt < 4; ++kt){
      s16x8 bh = *(const s16x8*)(wrh_p + kt*32);
      s16x8 bl = *(const s16x8*)(wrl_p + kt*32);
      acc = __builtin_amdgcn_mfma_f32_16x16x32_bf16(afh[kt], bh, acc, 0,0,0);
      acc = __builtin_amdgcn_mfma_f32_16x16x32_bf16(afh[kt], bl, acc, 0,0,0);
      acc = __builtin_amdgcn_mfma_f32_16x16x32_bf16(afl[kt], bh, acc, 0,0,0);
    }
    int mat = ncol >> 7;
    int colin = ncol & 127;
    float bias = (mat == 0) ? bq[colin] : (mat == 1 ? bk[colin] : bv[colin]);
    #pragma unroll
    for (int r = 0; r < 4; ++r){
      int m = wrh*16 + g*4 + r;        // D: row=(lane>>4)*4+reg, col=c16
      qkv[(row0 + m)*384 + ncol] = acc[r] + bias;
    }
  }
}

// Attention core (R7-proven VALU structure, QKV phase replaced by loads).
// One block per (b, head). q/k/v fp32 from qkv[row][384].
__global__ void attn_core_k(const float* __restrict__ qkv, float* __restrict__ o){
  int blk = blockIdx.x; int b = blk / NHEAD; int h = blk % NHEAD;
  int t = threadIdx.x;
  __shared__ float qs[SEQ][HDIM];
  __shared__ float ks[SEQ][HDIM];
  __shared__ float vs[SEQ][HDIM];
  __shared__ float ss[SEQ][SEQ+2];
  size_t base = (size_t)b*SEQ*384 + h*HDIM;
  for (int task = t; task < SEQ*HDIM; task += 256){
    int l = task >> 5, d = task & 31;
    const float* p = qkv + base + (size_t)l*384 + d;
    qs[l][d] = p[0];
    ks[l][d] = p[128];
    vs[l][d] = p[256];
  }
  __syncthreads();
  for (int task = t; task < SEQ*SEQ; task += 256){
    int l = task / SEQ, m = task % SEQ;
    float a = 0.f;
    #pragma unroll
    for (int d = 0; d < HDIM; ++d) a += qs[l][d]*ks[m][d];
    ss[l][m] = a * 0.17677669529663687f;  // 1/sqrt(32)
  }
  __syncthreads();
  if (t < SEQ){
    float mx = -1e30f;
    for (int m = 0; m < SEQ; ++m) mx = fmaxf(mx, ss[t][m]);
    float sum = 0.f;
    for (int m = 0; m < SEQ; ++m){ float e = __expf(ss[t][m]-mx); ss[t][m]=e; sum+=e; }
    float inv = 1.f/sum;
    for (int m = 0; m < SEQ; ++m) ss[t][m] *= inv;
  }
  __syncthreads();
  for (int task = t; task < SEQ*HDIM; task += 256){
    int l = task >> 5, d = task & 31;
    float a = 0.f;
    for (int m = 0; m < SEQ; ++m) a += ss[l][m]*vs[m][d];
    o[((size_t)b*SEQ+l)*HID + h*HDIM + d] = a;
  }
}

// O @ Wo^T + bo + residual + LN1. Clone of qkv_mfma_k with N=128 and
// LN epilogue (per-row reduce over c16 lanes + 2-wave LDS combine).
__global__ __launch_bounds__(256) void oproj_mfma_k(
    const float* __restrict__ o,
    const unsigned short* __restrict__ Woh_, const unsigned short* __restrict__ Wol_,
    const float* __restrict__ bo, const float* __restrict__ g1,
    const float* __restrict__ be1, float* x)
{
  __shared__ unsigned short Oh[32*128];
  __shared__ unsigned short Ol[32*128];
  __shared__ float red_s[2][2][16];
  __shared__ float red_q[2][2][16];
  int t = threadIdx.x;
  int wave = t >> 6, lane = t & 63;
  int g = lane >> 4, c16 = lane & 15;
  int wrh = wave >> 1;
  int wn  = wave & 1;
  size_t row0 = (size_t)blockIdx.x * 32;

  #pragma unroll
  for (int it = 0; it < 2; ++it){
    int idx8 = it*256 + t;
    int r = idx8 >> 4;
    int c8 = idx8 & 15;
    const float* src = o + (row0 + r)*HID + c8*8;
    float4 v0 = *(const float4*)(src);
    float4 v1 = *(const float4*)(src + 4);
    float f[8] = {v0.x,v0.y,v0.z,v0.w,v1.x,v1.y,v1.z,v1.w};
    s16x8 ph, pl;
    #pragma unroll
    for (int e = 0; e < 8; ++e){
      unsigned short hi = f2b(f[e]);
      ph[e] = (short)hi;
      pl[e] = (short)f2b(f[e] - b2f(hi));
    }
    int slot = c8 ^ (r & 15);
    *(s16x8*)((char*)Oh + r*256 + slot*16) = ph;
    *(s16x8*)((char*)Ol + r*256 + slot*16) = pl;
  }
  __syncthreads();

  int rloc = wrh*16 + c16;
  s16x8 afh[4], afl[4];
  #pragma unroll
  for (int kt = 0; kt < 4; ++kt){
    int slot = (kt*4 + g) ^ (rloc & 15);
    afh[kt] = *(const s16x8*)((const char*)Oh + rloc*256 + slot*16);
    afl[kt] = *(const s16x8*)((const char*)Ol + rloc*256 + slot*16);
  }

  float vals[4][4];   // [nt][r]
  #pragma unroll
  for (int nt = 0; nt < 4; ++nt){
    int jcol = (wn*4 + nt)*16 + c16;   // 0..127
    const unsigned short* wrh_p = Woh_ + (size_t)jcol*HID + g*8;
    const unsigned short* wrl_p = Wol_ + (size_t)jcol*HID + g*8;
    f32x4 acc = {0.f,0.f,0.f,0.f};
    #pragma unroll
    for (int kt = 0; kt < 4; ++kt){
      s16x8 bh = *(const s16x8*)(wrh_p + kt*32);
      s16x8 bl = *(const s16x8*)(wrl_p + kt*32);
      acc = __builtin_amdgcn_mfma_f32_16x16x32_bf16(afh[kt], bh, acc, 0,0,0);
      acc = __builtin_amdgcn_mfma_f32_16x16x32_bf16(afh[kt], bl, acc, 0,0,0);
      acc = __builtin_amdgcn_mfma_f32_16x16x32_bf16(afl[kt], bh, acc, 0,0,0);
    }
    float bias = bo[jcol];
    #pragma unroll
    for (int r = 0; r < 4; ++r){
      int m = wrh*16 + g*4 + r;
      vals[nt][r] = acc[r] + bias + x[(row0 + m)*HID + jcol];
    }
  }

  // LN stats: rows m = wrh*16 + g*4 + r; this lane holds 4 cols per row (nt).
  #pragma unroll
  for (int r = 0; r < 4; ++r){
    float s_ = vals[0][r] + vals[1][r] + vals[2][r] + vals[3][r];
    float q_ = vals[0][r]*vals[0][r] + vals[1][r]*vals[1][r]
             + vals[2][r]*vals[2][r] + vals[3][r]*vals[3][r];
    s_ += __shfl_xor(s_, 1, 64); q_ += __shfl_xor(q_, 1, 64);
    s_ += __shfl_xor(s_, 2, 64); q_ += __shfl_xor(q_, 2, 64);
    s_ += __shfl_xor(s_, 4, 64); q_ += __shfl_xor(q_, 4, 64);
    s_ += __shfl_xor(s_, 8, 64); q_ += __shfl_xor(q_, 8, 64);
    if (c16 == 0){
      red_s[wrh][wn][g*4 + r] = s_;
      red_q[wrh][wn][g*4 + r] = q_;
    }
  }
  __syncthreads();
  #pragma unroll
  for (int r = 0; r < 4; ++r){
    int m = wrh*16 + g*4 + r;
    float s_tot = red_s[wrh][0][g*4 + r] + red_s[wrh][1][g*4 + r];
    float q_tot = red_q[wrh][0][g*4 + r] + red_q[wrh][1][g*4 + r];
    float mean = s_tot * (1.f/HID);
    float var = q_tot * (1.f/HID) - mean*mean;
    float rstd = rsqrtf(var + 1e-5f);
    #pragma unroll
    for (int nt = 0; nt < 4; ++nt){
      int jcol = (wn*4 + nt)*16 + c16;
      x[(row0 + m)*HID + jcol] = (vals[nt][r]-mean)*rstd*g1[jcol] + be1[jcol];
    }
  }
}

// FFN via split-bf16 MFMA (hi/lo, 3-term): fp32-accurate. (R7, proven)
__global__ __launch_bounds__(256) void ffn_mfma2_k(
    const float* __restrict__ x,
    const unsigned short* __restrict__ W1h, const unsigned short* __restrict__ W1l,
    const float* __restrict__ b1,
    const unsigned short* __restrict__ W2h, const unsigned short* __restrict__ W2l,
    const float* __restrict__ b2, const float* __restrict__ gam,
    const float* __restrict__ bet, float* __restrict__ xout)
{
  __shared__ unsigned short Xh[32*128];
  __shared__ unsigned short Xl[32*128];
  __shared__ unsigned short Hh[32*512];
  __shared__ unsigned short Hl[32*512];
  __shared__ float red_s[2][2][16];
  __shared__ float red_q[2][2][16];
  int t = threadIdx.x;
  int wave = t >> 6, lane = t & 63;
  int g = lane >> 4, c16 = lane & 15;
  int wrh = wave >> 1;
  int wn  = wave & 1;
  size_t row0 = (size_t)blockIdx.x * 32;

  #pragma unroll
  for (int it = 0; it < 2; ++it){
    int idx8 = it*256 + t;
    int r = idx8 >> 4;
    int c8 = idx8 & 15;
    const float* src = x + (row0 + r)*HID + c8*8;
    float4 v0 = *(const float4*)(src);
    float4 v1 = *(const float4*)(src + 4);
    float f[8] = {v0.x,v0.y,v0.z,v0.w,v1.x,v1.y,v1.z,v1.w};
    s16x8 ph, pl;
    #pragma unroll
    for (int e = 0; e < 8; ++e){
      unsigned short hi = f2b(f[e]);
      ph[e] = (short)hi;
      pl[e] = (short)f2b(f[e] - b2f(hi));
    }
    int slot = c8 ^ (r & 15);
    *(s16x8*)((char*)Xh + r*256 + slot*16) = ph;
    *(s16x8*)((char*)Xl + r*256 + slot*16) = pl;
  }
  __syncthreads();

  int rloc = wrh*16 + c16;
  s16x8 afh[4], afl[4];
  #pragma unroll
  for (int kt = 0; kt < 4; ++kt){
    int slot = (kt*4 + g) ^ (rloc & 15);
    afh[kt] = *(const s16x8*)((const char*)Xh + rloc*256 + slot*16);
    afl[kt] = *(const s16x8*)((const char*)Xl + rloc*256 + slot*16);
  }

  for (int nt = 0; nt < 16; ++nt){
    int ntg = wn*16 + nt;
    int nrow = ntg*16 + c16;
    const unsigned short* wrh_p = W1h + nrow*HID + g*8;
    const unsigned short* wrl_p = W1l + nrow*HID + g*8;
    f32x4 acc = {0.f,0.f,0.f,0.f};
    #pragma unroll
    for (int kt = 0; kt < 4; ++kt){
      s16x8 bh = *(const s16x8*)(wrh_p + kt*32);
      s16x8 bl = *(const s16x8*)(wrl_p + kt*32);
      acc = __builtin_amdgcn_mfma_f32_16x16x32_bf16(afh[kt], bh, acc, 0,0,0);
      acc = __builtin_amdgcn_mfma_f32_16x16x32_bf16(afh[kt], bl, acc, 0,0,0);
      acc = __builtin_amdgcn_mfma_f32_16x16x32_bf16(afl[kt], bh, acc, 0,0,0);
    }
    float bv = b1[nrow];
    #pragma unroll
    for (int r = 0; r < 4; ++r){
      int m = wrh*16 + g*4 + r;
      float h = fmaxf(acc[r] + bv, 0.f);
      unsigned short hh = f2b(h);
      unsigned short hl = f2b(h - b2f(hh));
      int colb = nrow*2;
      int byteoff = m*1024 + (((((colb>>4) ^ (m & 15))<<4)) | (colb & 15));
      *(unsigned short*)((char*)Hh + byteoff) = hh;
      *(unsigned short*)((char*)Hl + byteoff) = hl;
    }
  }
  __syncthreads();

  f32x4 acc2[4];
  #pragma unroll
  for (int i = 0; i < 4; ++i) acc2[i] = (f32x4){0.f,0.f,0.f,0.f};
  int hrow = wrh*16 + c16;
  for (int kt2 = 0; kt2 < 16; ++kt2){
    int slot = (kt2*4 + g) ^ (hrow & 15);
    s16x8 hfh = *(const s16x8*)((const char*)Hh + hrow*1024 + slot*16);
    s16x8 hfl = *(const s16x8*)((const char*)Hl + hrow*1024 + slot*16);
    #pragma unroll
    for (int nt2 = 0; nt2 < 4; ++nt2){
      int jrow = (wn*4 + nt2)*16 + c16;
      s16x8 wfh = *(const s16x8*)(W2h + (size_t)jrow*INNER + kt2*32 + g*8);
      s16x8 wfl = *(const s16x8*)(W2l + (size_t)jrow*INNER + kt2*32 + g*8);
      acc2[nt2] = __builtin_amdgcn_mfma_f32_16x16x32_bf16(wfh, hfh, acc2[nt2], 0,0,0);
      acc2[nt2] = __builtin_amdgcn_mfma_f32_16x16x32_bf16(wfh, hfl, acc2[nt2], 0,0,0);
      acc2[nt2] = __builtin_amdgcn_mfma_f32_16x16x32_bf16(wfl, hfh, acc2[nt2], 0,0,0);
    }
  }

  size_t grow = row0 + (size_t)hrow;
  const float* xr = x + grow*HID;
  float vals[16];
  float s = 0.f, q = 0.f;
  #pragma unroll
  for (int nt2 = 0; nt2 < 4; ++nt2){
    #pragma unroll
    for (int r = 0; r < 4; ++r){
      int j = (wn*4 + nt2)*16 + g*4 + r;
      float v = acc2[nt2][r] + b2[j] + xr[j];
      vals[nt2*4+r] = v;
      s += v; q += v*v;
    }
  }
  s += __shfl_xor(s, 16, 64);
  s += __shfl_xor(s, 32, 64);
  q += __shfl_xor(q, 16, 64);
  q += __shfl_xor(q, 32, 64);
  if (g == 0){
    red_s[wrh][wn][c16] = s;
    red_q[wrh][wn][c16] = q;
  }
  __syncthreads();
  float s_tot = red_s[wrh][0][c16] + red_s[wrh][1][c16];
  float q_tot = red_q[wrh][0][c16] + red_q[wrh][1][c16];
  float mean = s_tot * (1.f/HID);
  float var = q_tot * (1.f/HID) - mean*mean;
  float rstd = rsqrtf(var + 1e-5f);
  float* orow = xout + grow*HID;
  #pragma unroll
  for (int nt2 = 0; nt2 < 4; ++nt2){
    #pragma unroll
    for (int r = 0; r < 4; ++r){
      int j = (wn*4 + nt2)*16 + g*4 + r;
      orow[j] = (vals[nt2*4+r]-mean)*rstd*gam[j] + bet[j];
    }
  }
}

// attention pooling + session vector. One block (128 thr) per batch elem.
__global__ void final_k(const float* __restrict__ x, const float* __restrict__ attW,
                        const float* __restrict__ attb, const float* __restrict__ sessW,
                        const float* __restrict__ sessb, float* __restrict__ sess){
  int b = blockIdx.x; int t = threadIdx.x;
  __shared__ float av[SEQ];
  __shared__ __align__(16) float cat[256];
  const float* xb = x + (size_t)b*SEQ*HID;
  if (t < SEQ){
    float a = attb[0];
    for (int c = 0; c < HID; ++c) a += xb[t*HID + c]*attW[c];
    av[t] = a;
  }
  __syncthreads();
  if (t == 0){
    float s = 0.f;
    for (int l = 0; l < SEQ; ++l) s += av[l];
    float inv = 1.f/s;
    for (int l = 0; l < SEQ; ++l) av[l] *= inv;
  }
  __syncthreads();
  float gacc = 0.f;
  for (int l = 0; l < SEQ; ++l) gacc += xb[l*HID + t]*av[l];
  cat[t] = xb[49*HID + t];
  cat[128+t] = gacc;
  __syncthreads();
  float acc = sessb[t];
  const float4* w = (const float4*)(sessW + (size_t)t*256);
  const float4* c4 = (const float4*)cat;
  #pragma unroll 8
  for (int j = 0; j < 64; ++j){
    float4 wv=w[j]; float4 cv=c4[j];
    acc += wv.x*cv.x + wv.y*cv.y + wv.z*cv.z + wv.w*cv.w;
  }
  sess[(size_t)b*HID + t] = acc;
}

// logits = sess @ emb[1:].T   (2048 x 49999, K=128)
__global__ void logits_k(const float* __restrict__ sess, const float* __restrict__ emb,
                         float* __restrict__ out){
  int t = threadIdx.x;
  int n0 = blockIdx.x * 256;
  int r0 = blockIdx.y * LROWS;
  __shared__ __align__(16) float ss[LROWS][HID];
  float* ssf = (float*)ss;
  for (int i = t; i < LROWS*HID; i += 256) ssf[i] = sess[(size_t)r0*HID + i];
  __syncthreads();
  int n = n0 + t;
  if (n >= NOUT) return;
  const float4* er = (const float4*)(emb + (size_t)(1+n)*HID);
  float acc[LROWS];
  #pragma unroll
  for (int r = 0; r < LROWS; ++r) acc[r] = 0.f;
  for (int c4i = 0; c4i < 32; ++c4i){
    float4 e = er[c4i];
    int c = c4i*4;
    #pragma unroll
    for (int r = 0; r < LROWS; ++r){
      acc[r] += e.x*ss[r][c] + e.y*ss[r][c+1] + e.z*ss[r][c+2] + e.w*ss[r][c+3];
    }
  }
  #pragma unroll
  for (int r = 0; r < LROWS; ++r){
    out[(size_t)(r0+r)*NOUT + n] = acc[r];
  }
}

extern "C" void kernel_launch(void* const* d_in, const int* in_sizes, int n_in,
                              void* d_out, int out_size, void* d_ws, size_t ws_size,
                              hipStream_t stream){
  const int*   ids  = (const int*)d_in[0];
  const float* A    = (const float*)d_in[1];
  const float* emb  = (const float*)d_in[2];
  const float* pos  = (const float*)d_in[3];
  const float* mixW = (const float*)d_in[4];
  const float* mixb = (const float*)d_in[5];
  const float* Wq   = (const float*)d_in[6];
  const float* bq   = (const float*)d_in[7];
  const float* Wk   = (const float*)d_in[8];
  const float* bk   = (const float*)d_in[9];
  const float* Wv   = (const float*)d_in[10];
  const float* bv   = (const float*)d_in[11];
  const float* Wo   = (const float*)d_in[12];
  const float* bo   = (const float*)d_in[13];
  const float* ln1g = (const float*)d_in[14];
  const float* ln1b = (const float*)d_in[15];
  const float* W1   = (const float*)d_in[16];
  const float* b1   = (const float*)d_in[17];
  const float* W2   = (const float*)d_in[18];
  const float* b2   = (const float*)d_in[19];
  const float* ln2g = (const float*)d_in[20];
  const float* ln2b = (const float*)d_in[21];
  const float* attW = (const float*)d_in[22];
  const float* attb = (const float*)d_in[23];
  const float* sessW= (const float*)d_in[24];
  const float* sessb= (const float*)d_in[25];
  float* out = (float*)d_out;

  float* xA   = (float*)d_ws;
  float* xB   = xA + (size_t)BSZ*SEQ*HID;
  float* sess = xB + (size_t)BSZ*SEQ*HID;
  // FFN hi/lo splits in the sess region (1MB; sess written only by final_k).
  unsigned short* W1h = (unsigned short*)sess;
  unsigned short* W1l = W1h + (size_t)2*INNER*HID;
  unsigned short* W2h = W1l + (size_t)2*INNER*HID;
  unsigned short* W2l = W2h + (size_t)2*INNER*HID;
  // Attention weights (512KB) in d_out tail; qkv/o scratch at d_out head.
  // All of d_out is overwritten by logits_k at the end.
  unsigned short* awb = (unsigned short*)(out + (size_t)out_size - 131072);
  unsigned short* Wqkvh = awb;
  unsigned short* Wqkvl = awb + 98304;
  unsigned short* Woh   = awb + 196608;
  unsigned short* Wol   = awb + 229376;
  float* qkvbuf = out;                               // 102400*384 floats
  float* obuf   = out + (size_t)102400*384;          // 102400*128 floats

  cvtw2_k<<<512, 256, 0, stream>>>(W1, W2, W1h, W1l, W2h, W2l);
  cvtw_qkvo_k<<<128, 256, 0, stream>>>(Wq, Wk, Wv, Wo, awb);
  embed_k<<<BSZ*SEQ, HID, 0, stream>>>(ids, emb, pos, xA);
  float* xc = xA; float* xn = xB;
  for (int i = 0; i < 2; ++i){
    mix_k<<<BSZ*SEQ, HID, 0, stream>>>(A, xc, mixW + (size_t)i*HID*2*HID, mixb + i*HID, xn);
    qkv_mfma_k<<<BSZ*SEQ/32, 256, 0, stream>>>(xn,
        Wqkvh + (size_t)i*384*HID, Wqkvl + (size_t)i*384*HID,
        bq + i*HID, bk + i*HID, bv + i*HID, qkvbuf);
    attn_core_k<<<BSZ*NHEAD, 256, 0, stream>>>(qkvbuf, obuf);
    oproj_mfma_k<<<BSZ*SEQ/32, 256, 0, stream>>>(obuf,
        Woh + (size_t)i*HID*HID, Wol + (size_t)i*HID*HID,
        bo + i*HID, ln1g + i*HID, ln1b + i*HID, xn);
    ffn_mfma2_k<<<BSZ*SEQ/32, 256, 0, stream>>>(xn,
        W1h + (size_t)i*INNER*HID, W1l + (size_t)i*INNER*HID, b1 + i*INNER,
        W2h + (size_t)i*INNER*HID, W2l + (size_t)i*INNER*HID, b2 + i*HID,
        ln2g + i*HID, ln2b + i*HID, xn);
    float* tmp = xc; xc = xn; xn = tmp;
  }
  final_k<<<BSZ, HID, 0, stream>>>(xc, attW, attb, sessW, sessb, sess);
  dim3 lgrid((NOUT + 255)/256, BSZ/LROWS);
  logits_k<<<lgrid, 256, 0, stream>>>(sess, emb, out);
}

// Round 11
// 2997.984 us; speedup vs baseline: 7.3254x; 2.0003x over previous
//
#include <hip/hip_runtime.h>

#define BSZ 2048
#define SEQ 50
#define HID 128
#define NHEAD 4
#define HDIM 32
#define INNER 512
#define NITEMS 50000
#define NOUT 49999
#define LROWS 32

typedef float f32x4 __attribute__((ext_vector_type(4)));
typedef short s16x8 __attribute__((ext_vector_type(8)));

__device__ __forceinline__ unsigned short f2b(float f){
  unsigned int u = __builtin_bit_cast(unsigned int, f);
  u = (u + 0x7FFFu + ((u >> 16) & 1u)) >> 16;
  return (unsigned short)u;
}
__device__ __forceinline__ float b2f(unsigned short h){
  unsigned int u = ((unsigned int)h) << 16;
  return __builtin_bit_cast(float, u);
}

__global__ void embed_k(const int* __restrict__ ids, const float* __restrict__ emb,
                        const float* __restrict__ pos, float* __restrict__ x){
  int row = blockIdx.x;          // b*SEQ + l
  int l = row % SEQ;
  int t = threadIdx.x;
  int id = ids[row];
  x[(size_t)row*HID + t] = emb[(size_t)id*HID + t] + pos[l*HID + t];
}

// split W1/W2 into bf16 hi/lo pairs (both layers)
__global__ void cvtw2_k(const float* __restrict__ W1, const float* __restrict__ W2,
                        unsigned short* __restrict__ W1h, unsigned short* __restrict__ W1l,
                        unsigned short* __restrict__ W2h, unsigned short* __restrict__ W2l){
  int i = blockIdx.x*256 + threadIdx.x;   // 2*512*128 = 131072 each
  float w1 = W1[i];
  unsigned short h1 = f2b(w1);
  W1h[i] = h1; W1l[i] = f2b(w1 - b2f(h1));
  float w2 = W2[i];
  unsigned short h2 = f2b(w2);
  W2h[i] = h2; W2l[i] = f2b(w2 - b2f(h2));
}

// Wq/Wk/Wv stacked into [2][384][128] hi/lo; Wo into [2][128][128] hi/lo.
__global__ void cvtw_qkvo_k(const float* __restrict__ Wq, const float* __restrict__ Wk,
                            const float* __restrict__ Wv, const float* __restrict__ Wo,
                            unsigned short* __restrict__ dst){
  int i = blockIdx.x*256 + threadIdx.x;   // 0..32767 (2 layers x 128 x 128)
  int l = i >> 14;
  int rc = i & 16383;
  unsigned short* Wqkvh = dst;                 // 98304 ushorts
  unsigned short* Wqkvl = dst + 98304;
  unsigned short* Woh   = dst + 196608;        // 32768
  unsigned short* Wol   = dst + 229376;
  size_t base = (size_t)l*384*128;
  float w; unsigned short h;
  w = Wq[i]; h = f2b(w); Wqkvh[base + rc]         = h; Wqkvl[base + rc]         = f2b(w - b2f(h));
  w = Wk[i]; h = f2b(w); Wqkvh[base + 16384 + rc] = h; Wqkvl[base + 16384 + rc] = f2b(w - b2f(h));
  w = Wv[i]; h = f2b(w); Wqkvh[base + 32768 + rc] = h; Wqkvl[base + 32768 + rc] = f2b(w - b2f(h));
  w = Wo[i]; h = f2b(w); Woh[i] = h; Wol[i] = f2b(w - b2f(h));
}

// mixW [2][128][256] -> hi/lo
__global__ void cvtmix_k(const float* __restrict__ mixW,
                         unsigned short* __restrict__ mWh, unsigned short* __restrict__ mWl){
  int i = blockIdx.x*256 + threadIdx.x;   // 0..65535
  float w = mixW[i];
  unsigned short h = f2b(w);
  mWh[i] = h; mWl[i] = f2b(w - b2f(h));
}

// mix via MFMA: one block per batch elem. Phase 1: bmm (cat = [A_in@x, A_out@x])
// with A and x^T staged hi/lo; Phase 2: cat @ mixW^T + mixb.
// All 3-term hi/lo (fp32-accurate).
__global__ __launch_bounds__(256) void mix_mfma_k(
    const float* __restrict__ A, const float* __restrict__ x,
    const unsigned short* __restrict__ mWh, const unsigned short* __restrict__ mWl,
    const float* __restrict__ mixb, float* __restrict__ xout)
{
  __shared__ __align__(16) char smem[65536];
  char* xTh = smem;          // 16KB: 128 rows x 128B (64 bf16/row), slot=chunk^(d&7)
  char* xTl = smem + 16384;  // 16KB
  char* Ah  = smem + 32768;  // 16KB: 64 rows x 256B (128 bf16/row), slot=chunk^(l&15)
  char* Al  = smem + 49152;  // 16KB
  char* Ch  = smem;          // 32KB: 64 rows x 512B (256 bf16/row), slot=chunk^(l&15)  [aliases xT]
  char* Cl  = smem + 32768;  // 32KB [aliases A]

  int t = threadIdx.x;
  int wave = t >> 6, lane = t & 63;
  int g = lane >> 4, c16 = lane & 15;
  int b = blockIdx.x;
  size_t xbase = (size_t)b * SEQ * HID;

  // ---- zero phase-1 LDS (padding correctness) ----
  {
    s16x8 z = {0,0,0,0,0,0,0,0};
    #pragma unroll
    for (int it = 0; it < 16; ++it)
      *(s16x8*)(smem + (it*256 + t)*16) = z;
  }
  __syncthreads();

  // ---- stage x^T hi/lo: x[r][c] -> xT[d=c][m=r], m>=50 stays zero ----
  for (int task = t; task < SEQ*32; task += 256){   // 1600 float4 tasks
    int r = task >> 5, c4 = task & 31;
    float4 v = *(const float4*)(x + xbase + (size_t)r*HID + c4*4);
    float f[4] = {v.x, v.y, v.z, v.w};
    #pragma unroll
    for (int i = 0; i < 4; ++i){
      int d = c4*4 + i;
      unsigned short hi = f2b(f[i]);
      unsigned short lo = f2b(f[i] - b2f(hi));
      int off = d*128 + ((((r >> 3) ^ (d & 7))<<4)) + (r & 7)*2;
      *(unsigned short*)(xTh + off) = hi;
      *(unsigned short*)(xTl + off) = lo;
    }
  }
  // ---- stage A' hi/lo: row l cols 0..63 = A[l][0..49]+pad, 64..127 = A[l][50..99]+pad ----
  {
    int l = t >> 2, q = t & 3;            // 64 rows x 4 threads; rows >=50 skipped (stay 0)
    if (l < SEQ){
      const float* Ar = A + (size_t)(b*SEQ + l)*100;
      for (int j = q*25; j < q*25 + 25; ++j){   // j = 0..99
        float av = Ar[j];
        int col = (j < SEQ) ? j : (64 + (j - SEQ));
        unsigned short hi = f2b(av);
        unsigned short lo = f2b(av - b2f(hi));
        int off = l*256 + ((((col >> 3) ^ (l & 15))<<4)) + (col & 7)*2;
        *(unsigned short*)(Ah + off) = hi;
        *(unsigned short*)(Al + off) = lo;
      }
    }
  }
  __syncthreads();

  // ---- bmm: wave handles mtile = wave (rows wave*16..+15), all 8 ntiles ----
  int rA = wave*16 + c16;
  s16x8 aih[2], ail[2], aoh[2], aol[2];
  #pragma unroll
  for (int kt = 0; kt < 2; ++kt){
    int ci = kt*4 + g;                 // in-half chunks 0..7
    int co = 8 + kt*4 + g;             // out-half chunks 8..15
    int offi = rA*256 + ((ci ^ (rA & 15))<<4);
    int offo = rA*256 + ((co ^ (rA & 15))<<4);
    aih[kt] = *(const s16x8*)(Ah + offi);
    ail[kt] = *(const s16x8*)(Al + offi);
    aoh[kt] = *(const s16x8*)(Ah + offo);
    aol[kt] = *(const s16x8*)(Al + offo);
  }
  f32x4 accin[8], accout[8];
  #pragma unroll
  for (int nt = 0; nt < 8; ++nt){ accin[nt] = (f32x4){0,0,0,0}; accout[nt] = (f32x4){0,0,0,0}; }
  #pragma unroll
  for (int kt = 0; kt < 2; ++kt){
    #pragma unroll
    for (int nt = 0; nt < 8; ++nt){
      int d = nt*16 + c16;
      int boff = d*128 + ((((kt*4 + g) ^ (d & 7)))<<4);
      s16x8 bh = *(const s16x8*)(xTh + boff);
      s16x8 bl = *(const s16x8*)(xTl + boff);
      accin[nt]  = __builtin_amdgcn_mfma_f32_16x16x32_bf16(aih[kt], bh, accin[nt], 0,0,0);
      accin[nt]  = __builtin_amdgcn_mfma_f32_16x16x32_bf16(aih[kt], bl, accin[nt], 0,0,0);
      accin[nt]  = __builtin_amdgcn_mfma_f32_16x16x32_bf16(ail[kt], bh, accin[nt], 0,0,0);
      accout[nt] = __builtin_amdgcn_mfma_f32_16x16x32_bf16(aoh[kt], bh, accout[nt], 0,0,0);
      accout[nt] = __builtin_amdgcn_mfma_f32_16x16x32_bf16(aoh[kt], bl, accout[nt], 0,0,0);
      accout[nt] = __builtin_amdgcn_mfma_f32_16x16x32_bf16(aol[kt], bh, accout[nt], 0,0,0);
    }
  }
  __syncthreads();   // xT/A now dead -> Ch/Cl alias them

  // ---- store cat hi/lo (rows l, 256 cols; in->0..127, out->128..255) ----
  #pragma unroll
  for (int nt = 0; nt < 8; ++nt){
    #pragma unroll
    for (int r = 0; r < 4; ++r){
      int l = wave*16 + g*4 + r;       // D: row=(lane>>4)*4+reg, col=c16
      int ci_ = nt*16 + c16;
      float vi = accin[nt][r];
      unsigned short hi = f2b(vi);
      int offi = l*512 + (((ci_ >> 3) ^ (l & 15))<<4) + (ci_ & 7)*2;
      *(unsigned short*)(Ch + offi) = hi;
      *(unsigned short*)(Cl + offi) = f2b(vi - b2f(hi));
      int co_ = 128 + nt*16 + c16;
      float vo = accout[nt][r];
      unsigned short ho = f2b(vo);
      int offo = l*512 + (((co_ >> 3) ^ (l & 15))<<4) + (co_ & 7)*2;
      *(unsigned short*)(Ch + offo) = ho;
      *(unsigned short*)(Cl + offo) = f2b(vo - b2f(ho));
    }
  }
  __syncthreads();

  // ---- GEMM2: xnew = cat @ mixW^T + mixb (K=256, 8 ksteps, 3-term) ----
  int rc = wave*16 + c16;
  f32x4 acc2[8];
  #pragma unroll
  for (int nt = 0; nt < 8; ++nt) acc2[nt] = (f32x4){0,0,0,0};
  for (int kt2 = 0; kt2 < 8; ++kt2){
    int slot = (kt2*4 + g) ^ (rc & 15);
    s16x8 cfh = *(const s16x8*)(Ch + rc*512 + slot*16);
    s16x8 cfl = *(const s16x8*)(Cl + rc*512 + slot*16);
    #pragma unroll
    for (int nt = 0; nt < 8; ++nt){
      int j = nt*16 + c16;
      s16x8 wh = *(const s16x8*)(mWh + (size_t)j*256 + kt2*32 + g*8);
      s16x8 wl = *(const s16x8*)(mWl + (size_t)j*256 + kt2*32 + g*8);
      acc2[nt] = __builtin_amdgcn_mfma_f32_16x16x32_bf16(cfh, wh, acc2[nt], 0,0,0);
      acc2[nt] = __builtin_amdgcn_mfma_f32_16x16x32_bf16(cfh, wl, acc2[nt], 0,0,0);
      acc2[nt] = __builtin_amdgcn_mfma_f32_16x16x32_bf16(cfl, wh, acc2[nt], 0,0,0);
    }
  }
  #pragma unroll
  for (int nt = 0; nt < 8; ++nt){
    int j = nt*16 + c16;
    float bb = mixb[j];
    #pragma unroll
    for (int r = 0; r < 4; ++r){
      int l = wave*16 + g*4 + r;
      if (l < SEQ) xout[xbase + (size_t)l*HID + j] = acc2[nt][r] + bb;
    }
  }
}

// QKV projection: proven GEMM1 clone. 32 rows/block, 4 waves.
__global__ __launch_bounds__(256) void qkv_mfma_k(
    const float* __restrict__ x,
    const unsigned short* __restrict__ Wh, const unsigned short* __restrict__ Wl,
    const float* __restrict__ bq, const float* __restrict__ bk,
    const float* __restrict__ bv, float* __restrict__ qkv)
{
  __shared__ unsigned short Xh[32*128];
  __shared__ unsigned short Xl[32*128];
  int t = threadIdx.x;
  int wave = t >> 6, lane = t & 63;
  int g = lane >> 4, c16 = lane & 15;
  int wrh = wave >> 1;
  int wn  = wave & 1;
  size_t row0 = (size_t)blockIdx.x * 32;

  #pragma unroll
  for (int it = 0; it < 2; ++it){
    int idx8 = it*256 + t;
    int r = idx8 >> 4;
    int c8 = idx8 & 15;
    const float* src = x + (row0 + r)*HID + c8*8;
    float4 v0 = *(const float4*)(src);
    float4 v1 = *(const float4*)(src + 4);
    float f[8] = {v0.x,v0.y,v0.z,v0.w,v1.x,v1.y,v1.z,v1.w};
    s16x8 ph, pl;
    #pragma unroll
    for (int e = 0; e < 8; ++e){
      unsigned short hi = f2b(f[e]);
      ph[e] = (short)hi;
      pl[e] = (short)f2b(f[e] - b2f(hi));
    }
    int slot = c8 ^ (r & 15);
    *(s16x8*)((char*)Xh + r*256 + slot*16) = ph;
    *(s16x8*)((char*)Xl + r*256 + slot*16) = pl;
  }
  __syncthreads();

  int rloc = wrh*16 + c16;
  s16x8 afh[4], afl[4];
  #pragma unroll
  for (int kt = 0; kt < 4; ++kt){
    int slot = (kt*4 + g) ^ (rloc & 15);
    afh[kt] = *(const s16x8*)((const char*)Xh + rloc*256 + slot*16);
    afl[kt] = *(const s16x8*)((const char*)Xl + rloc*256 + slot*16);
  }

  for (int nt = 0; nt < 12; ++nt){
    int tile = wn*12 + nt;
    int ncol = tile*16 + c16;          // 0..383
    const unsigned short* wrh_p = Wh + (size_t)ncol*HID + g*8;
    const unsigned short* wrl_p = Wl + (size_t)ncol*HID + g*8;
    f32x4 acc = {0.f,0.f,0.f,0.f};
    #pragma unroll
    for (int kt = 0; kt < 4; ++kt){
      s16x8 bh = *(const s16x8*)(wrh_p + kt*32);
      s16x8 bl = *(const s16x8*)(wrl_p + kt*32);
      acc = __builtin_amdgcn_mfma_f32_16x16x32_bf16(afh[kt], bh, acc, 0,0,0);
      acc = __builtin_amdgcn_mfma_f32_16x16x32_bf16(afh[kt], bl, acc, 0,0,0);
      acc = __builtin_amdgcn_mfma_f32_16x16x32_bf16(afl[kt], bh, acc, 0,0,0);
    }
    int mat = ncol >> 7;
    int colin = ncol & 127;
    float bias = (mat == 0) ? bq[colin] : (mat == 1 ? bk[colin] : bv[colin]);
    #pragma unroll
    for (int r = 0; r < 4; ++r){
      int m = wrh*16 + g*4 + r;
      qkv[(row0 + m)*384 + ncol] = acc[r] + bias;
    }
  }
}

// Attention core (proven VALU structure). One block per (b, head).
__global__ void attn_core_k(const float* __restrict__ qkv, float* __restrict__ o){
  int blk = blockIdx.x; int b = blk / NHEAD; int h = blk % NHEAD;
  int t = threadIdx.x;
  __shared__ float qs[SEQ][HDIM];
  __shared__ float ks[SEQ][HDIM];
  __shared__ float vs[SEQ][HDIM];
  __shared__ float ss[SEQ][SEQ+2];
  size_t base = (size_t)b*SEQ*384 + h*HDIM;
  for (int task = t; task < SEQ*HDIM; task += 256){
    int l = task >> 5, d = task & 31;
    const float* p = qkv + base + (size_t)l*384 + d;
    qs[l][d] = p[0];
    ks[l][d] = p[128];
    vs[l][d] = p[256];
  }
  __syncthreads();
  for (int task = t; task < SEQ*SEQ; task += 256){
    int l = task / SEQ, m = task % SEQ;
    float a = 0.f;
    #pragma unroll
    for (int d = 0; d < HDIM; ++d) a += qs[l][d]*ks[m][d];
    ss[l][m] = a * 0.17677669529663687f;  // 1/sqrt(32)
  }
  __syncthreads();
  if (t < SEQ){
    float mx = -1e30f;
    for (int m = 0; m < SEQ; ++m) mx = fmaxf(mx, ss[t][m]);
    float sum = 0.f;
    for (int m = 0; m < SEQ; ++m){ float e = __expf(ss[t][m]-mx); ss[t][m]=e; sum+=e; }
    float inv = 1.f/sum;
    for (int m = 0; m < SEQ; ++m) ss[t][m] *= inv;
  }
  __syncthreads();
  for (int task = t; task < SEQ*HDIM; task += 256){
    int l = task >> 5, d = task & 31;
    float a = 0.f;
    for (int m = 0; m < SEQ; ++m) a += ss[l][m]*vs[m][d];
    o[((size_t)b*SEQ+l)*HID + h*HDIM + d] = a;
  }
}

// O @ Wo^T + bo + residual + LN1 (proven).
__global__ __launch_bounds__(256) void oproj_mfma_k(
    const float* __restrict__ o,
    const unsigned short* __restrict__ Woh_, const unsigned short* __restrict__ Wol_,
    const float* __restrict__ bo, const float* __restrict__ g1,
    const float* __restrict__ be1, float* x)
{
  __shared__ unsigned short Oh[32*128];
  __shared__ unsigned short Ol[32*128];
  __shared__ float red_s[2][2][16];
  __shared__ float red_q[2][2][16];
  int t = threadIdx.x;
  int wave = t >> 6, lane = t & 63;
  int g = lane >> 4, c16 = lane & 15;
  int wrh = wave >> 1;
  int wn  = wave & 1;
  size_t row0 = (size_t)blockIdx.x * 32;

  #pragma unroll
  for (int it = 0; it < 2; ++it){
    int idx8 = it*256 + t;
    int r = idx8 >> 4;
    int c8 = idx8 & 15;
    const float* src = o + (row0 + r)*HID + c8*8;
    float4 v0 = *(const float4*)(src);
    float4 v1 = *(const float4*)(src + 4);
    float f[8] = {v0.x,v0.y,v0.z,v0.w,v1.x,v1.y,v1.z,v1.w};
    s16x8 ph, pl;
    #pragma unroll
    for (int e = 0; e < 8; ++e){
      unsigned short hi = f2b(f[e]);
      ph[e] = (short)hi;
      pl[e] = (short)f2b(f[e] - b2f(hi));
    }
    int slot = c8 ^ (r & 15);
    *(s16x8*)((char*)Oh + r*256 + slot*16) = ph;
    *(s16x8*)((char*)Ol + r*256 + slot*16) = pl;
  }
  __syncthreads();

  int rloc = wrh*16 + c16;
  s16x8 afh[4], afl[4];
  #pragma unroll
  for (int kt = 0; kt < 4; ++kt){
    int slot = (kt*4 + g) ^ (rloc & 15);
    afh[kt] = *(const s16x8*)((const char*)Oh + rloc*256 + slot*16);
    afl[kt] = *(const s16x8*)((const char*)Ol + rloc*256 + slot*16);
  }

  float vals[4][4];   // [nt][r]
  #pragma unroll
  for (int nt = 0; nt < 4; ++nt){
    int jcol = (wn*4 + nt)*16 + c16;   // 0..127
    const unsigned short* wrh_p = Woh_ + (size_t)jcol*HID + g*8;
    const unsigned short* wrl_p = Wol_ + (size_t)jcol*HID + g*8;
    f32x4 acc = {0.f,0.f,0.f,0.f};
    #pragma unroll
    for (int kt = 0; kt < 4; ++kt){
      s16x8 bh = *(const s16x8*)(wrh_p + kt*32);
      s16x8 bl = *(const s16x8*)(wrl_p + kt*32);
      acc = __builtin_amdgcn_mfma_f32_16x16x32_bf16(afh[kt], bh, acc, 0,0,0);
      acc = __builtin_amdgcn_mfma_f32_16x16x32_bf16(afh[kt], bl, acc, 0,0,0);
      acc = __builtin_amdgcn_mfma_f32_16x16x32_bf16(afl[kt], bh, acc, 0,0,0);
    }
    float bias = bo[jcol];
    #pragma unroll
    for (int r = 0; r < 4; ++r){
      int m = wrh*16 + g*4 + r;
      vals[nt][r] = acc[r] + bias + x[(row0 + m)*HID + jcol];
    }
  }

  #pragma unroll
  for (int r = 0; r < 4; ++r){
    float s_ = vals[0][r] + vals[1][r] + vals[2][r] + vals[3][r];
    float q_ = vals[0][r]*vals[0][r] + vals[1][r]*vals[1][r]
             + vals[2][r]*vals[2][r] + vals[3][r]*vals[3][r];
    s_ += __shfl_xor(s_, 1, 64); q_ += __shfl_xor(q_, 1, 64);
    s_ += __shfl_xor(s_, 2, 64); q_ += __shfl_xor(q_, 2, 64);
    s_ += __shfl_xor(s_, 4, 64); q_ += __shfl_xor(q_, 4, 64);
    s_ += __shfl_xor(s_, 8, 64); q_ += __shfl_xor(q_, 8, 64);
    if (c16 == 0){
      red_s[wrh][wn][g*4 + r] = s_;
      red_q[wrh][wn][g*4 + r] = q_;
    }
  }
  __syncthreads();
  #pragma unroll
  for (int r = 0; r < 4; ++r){
    int m = wrh*16 + g*4 + r;
    float s_tot = red_s[wrh][0][g*4 + r] + red_s[wrh][1][g*4 + r];
    float q_tot = red_q[wrh][0][g*4 + r] + red_q[wrh][1][g*4 + r];
    float mean = s_tot * (1.f/HID);
    float var = q_tot * (1.f/HID) - mean*mean;
    float rstd = rsqrtf(var + 1e-5f);
    #pragma unroll
    for (int nt = 0; nt < 4; ++nt){
      int jcol = (wn*4 + nt)*16 + c16;
      x[(row0 + m)*HID + jcol] = (vals[nt][r]-mean)*rstd*g1[jcol] + be1[jcol];
    }
  }
}

// FFN via split-bf16 MFMA (hi/lo, 3-term): fp32-accurate. (proven)
__global__ __launch_bounds__(256) void ffn_mfma2_k(
    const float* __restrict__ x,
    const unsigned short* __restrict__ W1h, const unsigned short* __restrict__ W1l,
    const float* __restrict__ b1,
    const unsigned short* __restrict__ W2h, const unsigned short* __restrict__ W2l,
    const float* __restrict__ b2, const float* __restrict__ gam,
    const float* __restrict__ bet, float* __restrict__ xout)
{
  __shared__ unsigned short Xh[32*128];
  __shared__ unsigned short Xl[32*128];
  __shared__ unsigned short Hh[32*512];
  __shared__ unsigned short Hl[32*512];
  __shared__ float red_s[2][2][16];
  __shared__ float red_q[2][2][16];
  int t = threadIdx.x;
  int wave = t >> 6, lane = t & 63;
  int g = lane >> 4, c16 = lane & 15;
  int wrh = wave >> 1;
  int wn  = wave & 1;
  size_t row0 = (size_t)blockIdx.x * 32;

  #pragma unroll
  for (int it = 0; it < 2; ++it){
    int idx8 = it*256 + t;
    int r = idx8 >> 4;
    int c8 = idx8 & 15;
    const float* src = x + (row0 + r)*HID + c8*8;
    float4 v0 = *(const float4*)(src);
    float4 v1 = *(const float4*)(src + 4);
    float f[8] = {v0.x,v0.y,v0.z,v0.w,v1.x,v1.y,v1.z,v1.w};
    s16x8 ph, pl;
    #pragma unroll
    for (int e = 0; e < 8; ++e){
      unsigned short hi = f2b(f[e]);
      ph[e] = (short)hi;
      pl[e] = (short)f2b(f[e] - b2f(hi));
    }
    int slot = c8 ^ (r & 15);
    *(s16x8*)((char*)Xh + r*256 + slot*16) = ph;
    *(s16x8*)((char*)Xl + r*256 + slot*16) = pl;
  }
  __syncthreads();

  int rloc = wrh*16 + c16;
  s16x8 afh[4], afl[4];
  #pragma unroll
  for (int kt = 0; kt < 4; ++kt){
    int slot = (kt*4 + g) ^ (rloc & 15);
    afh[kt] = *(const s16x8*)((const char*)Xh + rloc*256 + slot*16);
    afl[kt] = *(const s16x8*)((const char*)Xl + rloc*256 + slot*16);
  }

  for (int nt = 0; nt < 16; ++nt){
    int ntg = wn*16 + nt;
    int nrow = ntg*16 + c16;
    const unsigned short* wrh_p = W1h + nrow*HID + g*8;
    const unsigned short* wrl_p = W1l + nrow*HID + g*8;
    f32x4 acc = {0.f,0.f,0.f,0.f};
    #pragma unroll
    for (int kt = 0; kt < 4; ++kt){
      s16x8 bh = *(const s16x8*)(wrh_p + kt*32);
      s16x8 bl = *(const s16x8*)(wrl_p + kt*32);
      acc = __builtin_amdgcn_mfma_f32_16x16x32_bf16(afh[kt], bh, acc, 0,0,0);
      acc = __builtin_amdgcn_mfma_f32_16x16x32_bf16(afh[kt], bl, acc, 0,0,0);
      acc = __builtin_amdgcn_mfma_f32_16x16x32_bf16(afl[kt], bh, acc, 0,0,0);
    }
    float bv = b1[nrow];
    #pragma unroll
    for (int r = 0; r < 4; ++r){
      int m = wrh*16 + g*4 + r;
      float h = fmaxf(acc[r] + bv, 0.f);
      unsigned short hh = f2b(h);
      unsigned short hl = f2b(h - b2f(hh));
      int colb = nrow*2;
      int byteoff = m*1024 + (((((colb>>4) ^ (m & 15))<<4)) | (colb & 15));
      *(unsigned short*)((char*)Hh + byteoff) = hh;
      *(unsigned short*)((char*)Hl + byteoff) = hl;
    }
  }
  __syncthreads();

  f32x4 acc2[4];
  #pragma unroll
  for (int i = 0; i < 4; ++i) acc2[i] = (f32x4){0.f,0.f,0.f,0.f};
  int hrow = wrh*16 + c16;
  for (int kt2 = 0; kt2 < 16; ++kt2){
    int slot = (kt2*4 + g) ^ (hrow & 15);
    s16x8 hfh = *(const s16x8*)((const char*)Hh + hrow*1024 + slot*16);
    s16x8 hfl = *(const s16x8*)((const char*)Hl + hrow*1024 + slot*16);
    #pragma unroll
    for (int nt2 = 0; nt2 < 4; ++nt2){
      int jrow = (wn*4 + nt2)*16 + c16;
      s16x8 wfh = *(const s16x8*)(W2h + (size_t)jrow*INNER + kt2*32 + g*8);
      s16x8 wfl = *(const s16x8*)(W2l + (size_t)jrow*INNER + kt2*32 + g*8);
      acc2[nt2] = __builtin_amdgcn_mfma_f32_16x16x32_bf16(wfh, hfh, acc2[nt2], 0,0,0);
      acc2[nt2] = __builtin_amdgcn_mfma_f32_16x16x32_bf16(wfh, hfl, acc2[nt2], 0,0,0);
      acc2[nt2] = __builtin_amdgcn_mfma_f32_16x16x32_bf16(wfl, hfh, acc2[nt2], 0,0,0);
    }
  }

  size_t grow = row0 + (size_t)hrow;
  const float* xr = x + grow*HID;
  float vals[16];
  float s = 0.f, q = 0.f;
  #pragma unroll
  for (int nt2 = 0; nt2 < 4; ++nt2){
    #pragma unroll
    for (int r = 0; r < 4; ++r){
      int j = (wn*4 + nt2)*16 + g*4 + r;
      float v = acc2[nt2][r] + b2[j] + xr[j];
      vals[nt2*4+r] = v;
      s += v; q += v*v;
    }
  }
  s += __shfl_xor(s, 16, 64);
  s += __shfl_xor(s, 32, 64);
  q += __shfl_xor(q, 16, 64);
  q += __shfl_xor(q, 32, 64);
  if (g == 0){
    red_s[wrh][wn][c16] = s;
    red_q[wrh][wn][c16] = q;
  }
  __syncthreads();
  float s_tot = red_s[wrh][0][c16] + red_s[wrh][1][c16];
  float q_tot = red_q[wrh][0][c16] + red_q[wrh][1][c16];
  float mean = s_tot * (1.f/HID);
  float var = q_tot * (1.f/HID) - mean*mean;
  float rstd = rsqrtf(var + 1e-5f);
  float* orow = xout + grow*HID;
  #pragma unroll
  for (int nt2 = 0; nt2 < 4; ++nt2){
    #pragma unroll
    for (int r = 0; r < 4; ++r){
      int j = (wn*4 + nt2)*16 + g*4 + r;
      orow[j] = (vals[nt2*4+r]-mean)*rstd*gam[j] + bet[j];
    }
  }
}

// attention pooling + session vector. One block (128 thr) per batch elem.
__global__ void final_k(const float* __restrict__ x, const float* __restrict__ attW,
                        const float* __restrict__ attb, const float* __restrict__ sessW,
                        const float* __restrict__ sessb, float* __restrict__ sess){
  int b = blockIdx.x; int t = threadIdx.x;
  __shared__ float av[SEQ];
  __shared__ __align__(16) float cat[256];
  const float* xb = x + (size_t)b*SEQ*HID;
  if (t < SEQ){
    float a = attb[0];
    for (int c = 0; c < HID; ++c) a += xb[t*HID + c]*attW[c];
    av[t] = a;
  }
  __syncthreads();
  if (t == 0){
    float s = 0.f;
    for (int l = 0; l < SEQ; ++l) s += av[l];
    float inv = 1.f/s;
    for (int l = 0; l < SEQ; ++l) av[l] *= inv;
  }
  __syncthreads();
  float gacc = 0.f;
  for (int l = 0; l < SEQ; ++l) gacc += xb[l*HID + t]*av[l];
  cat[t] = xb[49*HID + t];
  cat[128+t] = gacc;
  __syncthreads();
  float acc = sessb[t];
  const float4* w = (const float4*)(sessW + (size_t)t*256);
  const float4* c4 = (const float4*)cat;
  #pragma unroll 8
  for (int j = 0; j < 64; ++j){
    float4 wv=w[j]; float4 cv=c4[j];
    acc += wv.x*cv.x + wv.y*cv.y + wv.z*cv.z + wv.w*cv.w;
  }
  sess[(size_t)b*HID + t] = acc;
}

// logits = sess @ emb[1:].T   (2048 x 49999, K=128)
__global__ void logits_k(const float* __restrict__ sess, const float* __restrict__ emb,
                         float* __restrict__ out){
  int t = threadIdx.x;
  int n0 = blockIdx.x * 256;
  int r0 = blockIdx.y * LROWS;
  __shared__ __align__(16) float ss[LROWS][HID];
  float* ssf = (float*)ss;
  for (int i = t; i < LROWS*HID; i += 256) ssf[i] = sess[(size_t)r0*HID + i];
  __syncthreads();
  int n = n0 + t;
  if (n >= NOUT) return;
  const float4* er = (const float4*)(emb + (size_t)(1+n)*HID);
  float acc[LROWS];
  #pragma unroll
  for (int r = 0; r < LROWS; ++r) acc[r] = 0.f;
  for (int c4i = 0; c4i < 32; ++c4i){
    float4 e = er[c4i];
    int c = c4i*4;
    #pragma unroll
    for (int r = 0; r < LROWS; ++r){
      acc[r] += e.x*ss[r][c] + e.y*ss[r][c+1] + e.z*ss[r][c+2] + e.w*ss[r][c+3];
    }
  }
  #pragma unroll
  for (int r = 0; r < LROWS; ++r){
    out[(size_t)(r0+r)*NOUT + n] = acc[r];
  }
}

extern "C" void kernel_launch(void* const* d_in, const int* in_sizes, int n_in,
                              void* d_out, int out_size, void* d_ws, size_t ws_size,
                              hipStream_t stream){
  const int*   ids  = (const int*)d_in[0];
  const float* A    = (const float*)d_in[1];
  const float* emb  = (const float*)d_in[2];
  const float* pos  = (const float*)d_in[3];
  const float* mixW = (const float*)d_in[4];
  const float* mixb = (const float*)d_in[5];
  const float* Wq   = (const float*)d_in[6];
  const float* bq   = (const float*)d_in[7];
  const float* Wk   = (const float*)d_in[8];
  const float* bk   = (const float*)d_in[9];
  const float* Wv   = (const float*)d_in[10];
  const float* bv   = (const float*)d_in[11];
  const float* Wo   = (const float*)d_in[12];
  const float* bo   = (const float*)d_in[13];
  const float* ln1g = (const float*)d_in[14];
  const float* ln1b = (const float*)d_in[15];
  const float* W1   = (const float*)d_in[16];
  const float* b1   = (const float*)d_in[17];
  const float* W2   = (const float*)d_in[18];
  const float* b2   = (const float*)d_in[19];
  const float* ln2g = (const float*)d_in[20];
  const float* ln2b = (const float*)d_in[21];
  const float* attW = (const float*)d_in[22];
  const float* attb = (const float*)d_in[23];
  const float* sessW= (const float*)d_in[24];
  const float* sessb= (const float*)d_in[25];
  float* out = (float*)d_out;

  float* xA   = (float*)d_ws;
  float* xB   = xA + (size_t)BSZ*SEQ*HID;
  float* sess = xB + (size_t)BSZ*SEQ*HID;
  // FFN hi/lo splits in the sess region (1MB; sess written only by final_k).
  unsigned short* W1h = (unsigned short*)sess;
  unsigned short* W1l = W1h + (size_t)2*INNER*HID;
  unsigned short* W2h = W1l + (size_t)2*INNER*HID;
  unsigned short* W2l = W2h + (size_t)2*INNER*HID;
  // Weight splits in d_out tail; qkv/o scratch at d_out head.
  // All of d_out is overwritten by logits_k at the end.
  unsigned short* awb = (unsigned short*)(out + (size_t)out_size - 131072);
  unsigned short* Wqkvh = awb;
  unsigned short* Wqkvl = awb + 98304;
  unsigned short* Woh   = awb + 196608;
  unsigned short* Wol   = awb + 229376;
  unsigned short* mwb = (unsigned short*)(out + (size_t)out_size - 131072 - 65536);
  unsigned short* mWh = mwb;              // [2][128][256]
  unsigned short* mWl = mwb + 65536;
  float* qkvbuf = out;                               // 102400*384 floats
  float* obuf   = out + (size_t)102400*384;          // 102400*128 floats

  cvtw2_k<<<512, 256, 0, stream>>>(W1, W2, W1h, W1l, W2h, W2l);
  cvtw_qkvo_k<<<128, 256, 0, stream>>>(Wq, Wk, Wv, Wo, awb);
  cvtmix_k<<<256, 256, 0, stream>>>(mixW, mWh, mWl);
  embed_k<<<BSZ*SEQ, HID, 0, stream>>>(ids, emb, pos, xA);
  float* xc = xA; float* xn = xB;
  for (int i = 0; i < 2; ++i){
    mix_mfma_k<<<BSZ, 256, 0, stream>>>(A, xc,
        mWh + (size_t)i*HID*256, mWl + (size_t)i*HID*256, mixb + i*HID, xn);
    qkv_mfma_k<<<BSZ*SEQ/32, 256, 0, stream>>>(xn,
        Wqkvh + (size_t)i*384*HID, Wqkvl + (size_t)i*384*HID,
        bq + i*HID, bk + i*HID, bv + i*HID, qkvbuf);
    attn_core_k<<<BSZ*NHEAD, 256, 0, stream>>>(qkvbuf, obuf);
    oproj_mfma_k<<<BSZ*SEQ/32, 256, 0, stream>>>(obuf,
        Woh + (size_t)i*HID*HID, Wol + (size_t)i*HID*HID,
        bo + i*HID, ln1g + i*HID, ln1b + i*HID, xn);
    ffn_mfma2_k<<<BSZ*SEQ/32, 256, 0, stream>>>(xn,
        W1h + (size_t)i*INNER*HID, W1l + (size_t)i*INNER*HID, b1 + i*INNER,
        W2h + (size_t)i*INNER*HID, W2l + (size_t)i*INNER*HID, b2 + i*HID,
        ln2g + i*HID, ln2b + i*HID, xn);
    float* tmp = xc; xc = xn; xn = tmp;
  }
  final_k<<<BSZ, HID, 0, stream>>>(xc, attW, attb, sessW, sessb, sess);
  dim3 lgrid((NOUT + 255)/256, BSZ/LROWS);
  logits_k<<<lgrid, 256, 0, stream>>>(sess, emb, out);
}

// Round 12
// 2517.806 us; speedup vs baseline: 8.7225x; 1.1907x over previous
//
#include <hip/hip_runtime.h>

#define BSZ 2048
#define SEQ 50
#define HID 128
#define NHEAD 4
#define HDIM 32
#define INNER 512
#define NITEMS 50000
#define NOUT 49999
#define NPAD 50048
#define LROWS 32

typedef float f32x4 __attribute__((ext_vector_type(4)));
typedef short s16x8 __attribute__((ext_vector_type(8)));

__device__ __forceinline__ unsigned short f2b(float f){
  unsigned int u = __builtin_bit_cast(unsigned int, f);
  u = (u + 0x7FFFu + ((u >> 16) & 1u)) >> 16;
  return (unsigned short)u;
}
__device__ __forceinline__ float b2f(unsigned short h){
  unsigned int u = ((unsigned int)h) << 16;
  return __builtin_bit_cast(float, u);
}

__global__ void embed_k(const int* __restrict__ ids, const float* __restrict__ emb,
                        const float* __restrict__ pos, float* __restrict__ x){
  int row = blockIdx.x;          // b*SEQ + l
  int l = row % SEQ;
  int t = threadIdx.x;
  int id = ids[row];
  x[(size_t)row*HID + t] = emb[(size_t)id*HID + t] + pos[l*HID + t];
}

// split W1/W2 into bf16 hi/lo pairs (both layers)
__global__ void cvtw2_k(const float* __restrict__ W1, const float* __restrict__ W2,
                        unsigned short* __restrict__ W1h, unsigned short* __restrict__ W1l,
                        unsigned short* __restrict__ W2h, unsigned short* __restrict__ W2l){
  int i = blockIdx.x*256 + threadIdx.x;   // 2*512*128 = 131072 each
  float w1 = W1[i];
  unsigned short h1 = f2b(w1);
  W1h[i] = h1; W1l[i] = f2b(w1 - b2f(h1));
  float w2 = W2[i];
  unsigned short h2 = f2b(w2);
  W2h[i] = h2; W2l[i] = f2b(w2 - b2f(h2));
}

// Wq/Wk/Wv stacked into [2][384][128] hi/lo; Wo into [2][128][128] hi/lo.
__global__ void cvtw_qkvo_k(const float* __restrict__ Wq, const float* __restrict__ Wk,
                            const float* __restrict__ Wv, const float* __restrict__ Wo,
                            unsigned short* __restrict__ dst){
  int i = blockIdx.x*256 + threadIdx.x;   // 0..32767 (2 layers x 128 x 128)
  int l = i >> 14;
  int rc = i & 16383;
  unsigned short* Wqkvh = dst;                 // 98304 ushorts
  unsigned short* Wqkvl = dst + 98304;
  unsigned short* Woh   = dst + 196608;        // 32768
  unsigned short* Wol   = dst + 229376;
  size_t base = (size_t)l*384*128;
  float w; unsigned short h;
  w = Wq[i]; h = f2b(w); Wqkvh[base + rc]         = h; Wqkvl[base + rc]         = f2b(w - b2f(h));
  w = Wk[i]; h = f2b(w); Wqkvh[base + 16384 + rc] = h; Wqkvl[base + 16384 + rc] = f2b(w - b2f(h));
  w = Wv[i]; h = f2b(w); Wqkvh[base + 32768 + rc] = h; Wqkvl[base + 32768 + rc] = f2b(w - b2f(h));
  w = Wo[i]; h = f2b(w); Woh[i] = h; Wol[i] = f2b(w - b2f(h));
}

// mixW [2][128][256] -> hi/lo
__global__ void cvtmix_k(const float* __restrict__ mixW,
                         unsigned short* __restrict__ mWh, unsigned short* __restrict__ mWl){
  int i = blockIdx.x*256 + threadIdx.x;   // 0..65535
  float w = mixW[i];
  unsigned short h = f2b(w);
  mWh[i] = h; mWl[i] = f2b(w - b2f(h));
}

// sess (2048x128) and emb[1:] (NOUT x 128, zero-padded to NPAD) -> hi/lo
__global__ void cvt_logits_k(const float* __restrict__ sess, const float* __restrict__ emb,
                             unsigned short* __restrict__ sessH, unsigned short* __restrict__ sessL,
                             unsigned short* __restrict__ embH, unsigned short* __restrict__ embL){
  int i = blockIdx.x*256 + threadIdx.x;   // 0 .. NPAD*128-1
  int n = i >> 7, k = i & 127;
  float w = (n < NOUT) ? emb[(size_t)(1+n)*HID + k] : 0.f;
  unsigned short h = f2b(w);
  embH[i] = h; embL[i] = f2b(w - b2f(h));
  if (i < BSZ*HID){
    float s = sess[i];
    unsigned short hs = f2b(s);
    sessH[i] = hs; sessL[i] = f2b(s - b2f(hs));
  }
}

// mix via MFMA: one block per batch elem (proven R11).
__global__ __launch_bounds__(256) void mix_mfma_k(
    const float* __restrict__ A, const float* __restrict__ x,
    const unsigned short* __restrict__ mWh, const unsigned short* __restrict__ mWl,
    const float* __restrict__ mixb, float* __restrict__ xout)
{
  __shared__ __align__(16) char smem[65536];
  char* xTh = smem;
  char* xTl = smem + 16384;
  char* Ah  = smem + 32768;
  char* Al  = smem + 49152;
  char* Ch  = smem;
  char* Cl  = smem + 32768;

  int t = threadIdx.x;
  int wave = t >> 6, lane = t & 63;
  int g = lane >> 4, c16 = lane & 15;
  int b = blockIdx.x;
  size_t xbase = (size_t)b * SEQ * HID;

  {
    s16x8 z = {0,0,0,0,0,0,0,0};
    #pragma unroll
    for (int it = 0; it < 16; ++it)
      *(s16x8*)(smem + (it*256 + t)*16) = z;
  }
  __syncthreads();

  for (int task = t; task < SEQ*32; task += 256){
    int r = task >> 5, c4 = task & 31;
    float4 v = *(const float4*)(x + xbase + (size_t)r*HID + c4*4);
    float f[4] = {v.x, v.y, v.z, v.w};
    #pragma unroll
    for (int i = 0; i < 4; ++i){
      int d = c4*4 + i;
      unsigned short hi = f2b(f[i]);
      unsigned short lo = f2b(f[i] - b2f(hi));
      int off = d*128 + ((((r >> 3) ^ (d & 7))<<4)) + (r & 7)*2;
      *(unsigned short*)(xTh + off) = hi;
      *(unsigned short*)(xTl + off) = lo;
    }
  }
  {
    int l = t >> 2, q = t & 3;
    if (l < SEQ){
      const float* Ar = A + (size_t)(b*SEQ + l)*100;
      for (int j = q*25; j < q*25 + 25; ++j){
        float av = Ar[j];
        int col = (j < SEQ) ? j : (64 + (j - SEQ));
        unsigned short hi = f2b(av);
        unsigned short lo = f2b(av - b2f(hi));
        int off = l*256 + ((((col >> 3) ^ (l & 15))<<4)) + (col & 7)*2;
        *(unsigned short*)(Ah + off) = hi;
        *(unsigned short*)(Al + off) = lo;
      }
    }
  }
  __syncthreads();

  int rA = wave*16 + c16;
  s16x8 aih[2], ail[2], aoh[2], aol[2];
  #pragma unroll
  for (int kt = 0; kt < 2; ++kt){
    int ci = kt*4 + g;
    int co = 8 + kt*4 + g;
    int offi = rA*256 + ((ci ^ (rA & 15))<<4);
    int offo = rA*256 + ((co ^ (rA & 15))<<4);
    aih[kt] = *(const s16x8*)(Ah + offi);
    ail[kt] = *(const s16x8*)(Al + offi);
    aoh[kt] = *(const s16x8*)(Ah + offo);
    aol[kt] = *(const s16x8*)(Al + offo);
  }
  f32x4 accin[8], accout[8];
  #pragma unroll
  for (int nt = 0; nt < 8; ++nt){ accin[nt] = (f32x4){0,0,0,0}; accout[nt] = (f32x4){0,0,0,0}; }
  #pragma unroll
  for (int kt = 0; kt < 2; ++kt){
    #pragma unroll
    for (int nt = 0; nt < 8; ++nt){
      int d = nt*16 + c16;
      int boff = d*128 + ((((kt*4 + g) ^ (d & 7)))<<4);
      s16x8 bh = *(const s16x8*)(xTh + boff);
      s16x8 bl = *(const s16x8*)(xTl + boff);
      accin[nt]  = __builtin_amdgcn_mfma_f32_16x16x32_bf16(aih[kt], bh, accin[nt], 0,0,0);
      accin[nt]  = __builtin_amdgcn_mfma_f32_16x16x32_bf16(aih[kt], bl, accin[nt], 0,0,0);
      accin[nt]  = __builtin_amdgcn_mfma_f32_16x16x32_bf16(ail[kt], bh, accin[nt], 0,0,0);
      accout[nt] = __builtin_amdgcn_mfma_f32_16x16x32_bf16(aoh[kt], bh, accout[nt], 0,0,0);
      accout[nt] = __builtin_amdgcn_mfma_f32_16x16x32_bf16(aoh[kt], bl, accout[nt], 0,0,0);
      accout[nt] = __builtin_amdgcn_mfma_f32_16x16x32_bf16(aol[kt], bh, accout[nt], 0,0,0);
    }
  }
  __syncthreads();

  #pragma unroll
  for (int nt = 0; nt < 8; ++nt){
    #pragma unroll
    for (int r = 0; r < 4; ++r){
      int l = wave*16 + g*4 + r;
      int ci_ = nt*16 + c16;
      float vi = accin[nt][r];
      unsigned short hi = f2b(vi);
      int offi = l*512 + (((ci_ >> 3) ^ (l & 15))<<4) + (ci_ & 7)*2;
      *(unsigned short*)(Ch + offi) = hi;
      *(unsigned short*)(Cl + offi) = f2b(vi - b2f(hi));
      int co_ = 128 + nt*16 + c16;
      float vo = accout[nt][r];
      unsigned short ho = f2b(vo);
      int offo = l*512 + (((co_ >> 3) ^ (l & 15))<<4) + (co_ & 7)*2;
      *(unsigned short*)(Ch + offo) = ho;
      *(unsigned short*)(Cl + offo) = f2b(vo - b2f(ho));
    }
  }
  __syncthreads();

  int rc = wave*16 + c16;
  f32x4 acc2[8];
  #pragma unroll
  for (int nt = 0; nt < 8; ++nt) acc2[nt] = (f32x4){0,0,0,0};
  for (int kt2 = 0; kt2 < 8; ++kt2){
    int slot = (kt2*4 + g) ^ (rc & 15);
    s16x8 cfh = *(const s16x8*)(Ch + rc*512 + slot*16);
    s16x8 cfl = *(const s16x8*)(Cl + rc*512 + slot*16);
    #pragma unroll
    for (int nt = 0; nt < 8; ++nt){
      int j = nt*16 + c16;
      s16x8 wh = *(const s16x8*)(mWh + (size_t)j*256 + kt2*32 + g*8);
      s16x8 wl = *(const s16x8*)(mWl + (size_t)j*256 + kt2*32 + g*8);
      acc2[nt] = __builtin_amdgcn_mfma_f32_16x16x32_bf16(cfh, wh, acc2[nt], 0,0,0);
      acc2[nt] = __builtin_amdgcn_mfma_f32_16x16x32_bf16(cfh, wl, acc2[nt], 0,0,0);
      acc2[nt] = __builtin_amdgcn_mfma_f32_16x16x32_bf16(cfl, wh, acc2[nt], 0,0,0);
    }
  }
  #pragma unroll
  for (int nt = 0; nt < 8; ++nt){
    int j = nt*16 + c16;
    float bb = mixb[j];
    #pragma unroll
    for (int r = 0; r < 4; ++r){
      int l = wave*16 + g*4 + r;
      if (l < SEQ) xout[xbase + (size_t)l*HID + j] = acc2[nt][r] + bb;
    }
  }
}

// QKV projection: proven GEMM1 clone. 32 rows/block, 4 waves.
__global__ __launch_bounds__(256) void qkv_mfma_k(
    const float* __restrict__ x,
    const unsigned short* __restrict__ Wh, const unsigned short* __restrict__ Wl,
    const float* __restrict__ bq, const float* __restrict__ bk,
    const float* __restrict__ bv, float* __restrict__ qkv)
{
  __shared__ unsigned short Xh[32*128];
  __shared__ unsigned short Xl[32*128];
  int t = threadIdx.x;
  int wave = t >> 6, lane = t & 63;
  int g = lane >> 4, c16 = lane & 15;
  int wrh = wave >> 1;
  int wn  = wave & 1;
  size_t row0 = (size_t)blockIdx.x * 32;

  #pragma unroll
  for (int it = 0; it < 2; ++it){
    int idx8 = it*256 + t;
    int r = idx8 >> 4;
    int c8 = idx8 & 15;
    const float* src = x + (row0 + r)*HID + c8*8;
    float4 v0 = *(const float4*)(src);
    float4 v1 = *(const float4*)(src + 4);
    float f[8] = {v0.x,v0.y,v0.z,v0.w,v1.x,v1.y,v1.z,v1.w};
    s16x8 ph, pl;
    #pragma unroll
    for (int e = 0; e < 8; ++e){
      unsigned short hi = f2b(f[e]);
      ph[e] = (short)hi;
      pl[e] = (short)f2b(f[e] - b2f(hi));
    }
    int slot = c8 ^ (r & 15);
    *(s16x8*)((char*)Xh + r*256 + slot*16) = ph;
    *(s16x8*)((char*)Xl + r*256 + slot*16) = pl;
  }
  __syncthreads();

  int rloc = wrh*16 + c16;
  s16x8 afh[4], afl[4];
  #pragma unroll
  for (int kt = 0; kt < 4; ++kt){
    int slot = (kt*4 + g) ^ (rloc & 15);
    afh[kt] = *(const s16x8*)((const char*)Xh + rloc*256 + slot*16);
    afl[kt] = *(const s16x8*)((const char*)Xl + rloc*256 + slot*16);
  }

  for (int nt = 0; nt < 12; ++nt){
    int tile = wn*12 + nt;
    int ncol = tile*16 + c16;          // 0..383
    const unsigned short* wrh_p = Wh + (size_t)ncol*HID + g*8;
    const unsigned short* wrl_p = Wl + (size_t)ncol*HID + g*8;
    f32x4 acc = {0.f,0.f,0.f,0.f};
    #pragma unroll
    for (int kt = 0; kt < 4; ++kt){
      s16x8 bh = *(const s16x8*)(wrh_p + kt*32);
      s16x8 bl = *(const s16x8*)(wrl_p + kt*32);
      acc = __builtin_amdgcn_mfma_f32_16x16x32_bf16(afh[kt], bh, acc, 0,0,0);
      acc = __builtin_amdgcn_mfma_f32_16x16x32_bf16(afh[kt], bl, acc, 0,0,0);
      acc = __builtin_amdgcn_mfma_f32_16x16x32_bf16(afl[kt], bh, acc, 0,0,0);
    }
    int mat = ncol >> 7;
    int colin = ncol & 127;
    float bias = (mat == 0) ? bq[colin] : (mat == 1 ? bk[colin] : bv[colin]);
    #pragma unroll
    for (int r = 0; r < 4; ++r){
      int m = wrh*16 + g*4 + r;
      qkv[(row0 + m)*384 + ncol] = acc[r] + bias;
    }
  }
}

// Attention core (proven VALU structure). One block per (b, head).
__global__ void attn_core_k(const float* __restrict__ qkv, float* __restrict__ o){
  int blk = blockIdx.x; int b = blk / NHEAD; int h = blk % NHEAD;
  int t = threadIdx.x;
  __shared__ float qs[SEQ][HDIM];
  __shared__ float ks[SEQ][HDIM];
  __shared__ float vs[SEQ][HDIM];
  __shared__ float ss[SEQ][SEQ+2];
  size_t base = (size_t)b*SEQ*384 + h*HDIM;
  for (int task = t; task < SEQ*HDIM; task += 256){
    int l = task >> 5, d = task & 31;
    const float* p = qkv + base + (size_t)l*384 + d;
    qs[l][d] = p[0];
    ks[l][d] = p[128];
    vs[l][d] = p[256];
  }
  __syncthreads();
  for (int task = t; task < SEQ*SEQ; task += 256){
    int l = task / SEQ, m = task % SEQ;
    float a = 0.f;
    #pragma unroll
    for (int d = 0; d < HDIM; ++d) a += qs[l][d]*ks[m][d];
    ss[l][m] = a * 0.17677669529663687f;  // 1/sqrt(32)
  }
  __syncthreads();
  if (t < SEQ){
    float mx = -1e30f;
    for (int m = 0; m < SEQ; ++m) mx = fmaxf(mx, ss[t][m]);
    float sum = 0.f;
    for (int m = 0; m < SEQ; ++m){ float e = __expf(ss[t][m]-mx); ss[t][m]=e; sum+=e; }
    float inv = 1.f/sum;
    for (int m = 0; m < SEQ; ++m) ss[t][m] *= inv;
  }
  __syncthreads();
  for (int task = t; task < SEQ*HDIM; task += 256){
    int l = task >> 5, d = task & 31;
    float a = 0.f;
    for (int m = 0; m < SEQ; ++m) a += ss[l][m]*vs[m][d];
    o[((size_t)b*SEQ+l)*HID + h*HDIM + d] = a;
  }
}

// O @ Wo^T + bo + residual + LN1 (proven).
__global__ __launch_bounds__(256) void oproj_mfma_k(
    const float* __restrict__ o,
    const unsigned short* __restrict__ Woh_, const unsigned short* __restrict__ Wol_,
    const float* __restrict__ bo, const float* __restrict__ g1,
    const float* __restrict__ be1, float* x)
{
  __shared__ unsigned short Oh[32*128];
  __shared__ unsigned short Ol[32*128];
  __shared__ float red_s[2][2][16];
  __shared__ float red_q[2][2][16];
  int t = threadIdx.x;
  int wave = t >> 6, lane = t & 63;
  int g = lane >> 4, c16 = lane & 15;
  int wrh = wave >> 1;
  int wn  = wave & 1;
  size_t row0 = (size_t)blockIdx.x * 32;

  #pragma unroll
  for (int it = 0; it < 2; ++it){
    int idx8 = it*256 + t;
    int r = idx8 >> 4;
    int c8 = idx8 & 15;
    const float* src = o + (row0 + r)*HID + c8*8;
    float4 v0 = *(const float4*)(src);
    float4 v1 = *(const float4*)(src + 4);
    float f[8] = {v0.x,v0.y,v0.z,v0.w,v1.x,v1.y,v1.z,v1.w};
    s16x8 ph, pl;
    #pragma unroll
    for (int e = 0; e < 8; ++e){
      unsigned short hi = f2b(f[e]);
      ph[e] = (short)hi;
      pl[e] = (short)f2b(f[e] - b2f(hi));
    }
    int slot = c8 ^ (r & 15);
    *(s16x8*)((char*)Oh + r*256 + slot*16) = ph;
    *(s16x8*)((char*)Ol + r*256 + slot*16) = pl;
  }
  __syncthreads();

  int rloc = wrh*16 + c16;
  s16x8 afh[4], afl[4];
  #pragma unroll
  for (int kt = 0; kt < 4; ++kt){
    int slot = (kt*4 + g) ^ (rloc & 15);
    afh[kt] = *(const s16x8*)((const char*)Oh + rloc*256 + slot*16);
    afl[kt] = *(const s16x8*)((const char*)Ol + rloc*256 + slot*16);
  }

  float vals[4][4];   // [nt][r]
  #pragma unroll
  for (int nt = 0; nt < 4; ++nt){
    int jcol = (wn*4 + nt)*16 + c16;   // 0..127
    const unsigned short* wrh_p = Woh_ + (size_t)jcol*HID + g*8;
    const unsigned short* wrl_p = Wol_ + (size_t)jcol*HID + g*8;
    f32x4 acc = {0.f,0.f,0.f,0.f};
    #pragma unroll
    for (int kt = 0; kt < 4; ++kt){
      s16x8 bh = *(const s16x8*)(wrh_p + kt*32);
      s16x8 bl = *(const s16x8*)(wrl_p + kt*32);
      acc = __builtin_amdgcn_mfma_f32_16x16x32_bf16(afh[kt], bh, acc, 0,0,0);
      acc = __builtin_amdgcn_mfma_f32_16x16x32_bf16(afh[kt], bl, acc, 0,0,0);
      acc = __builtin_amdgcn_mfma_f32_16x16x32_bf16(afl[kt], bh, acc, 0,0,0);
    }
    float bias = bo[jcol];
    #pragma unroll
    for (int r = 0; r < 4; ++r){
      int m = wrh*16 + g*4 + r;
      vals[nt][r] = acc[r] + bias + x[(row0 + m)*HID + jcol];
    }
  }

  #pragma unroll
  for (int r = 0; r < 4; ++r){
    float s_ = vals[0][r] + vals[1][r] + vals[2][r] + vals[3][r];
    float q_ = vals[0][r]*vals[0][r] + vals[1][r]*vals[1][r]
             + vals[2][r]*vals[2][r] + vals[3][r]*vals[3][r];
    s_ += __shfl_xor(s_, 1, 64); q_ += __shfl_xor(q_, 1, 64);
    s_ += __shfl_xor(s_, 2, 64); q_ += __shfl_xor(q_, 2, 64);
    s_ += __shfl_xor(s_, 4, 64); q_ += __shfl_xor(q_, 4, 64);
    s_ += __shfl_xor(s_, 8, 64); q_ += __shfl_xor(q_, 8, 64);
    if (c16 == 0){
      red_s[wrh][wn][g*4 + r] = s_;
      red_q[wrh][wn][g*4 + r] = q_;
    }
  }
  __syncthreads();
  #pragma unroll
  for (int r = 0; r < 4; ++r){
    int m = wrh*16 + g*4 + r;
    float s_tot = red_s[wrh][0][g*4 + r] + red_s[wrh][1][g*4 + r];
    float q_tot = red_q[wrh][0][g*4 + r] + red_q[wrh][1][g*4 + r];
    float mean = s_tot * (1.f/HID);
    float var = q_tot * (1.f/HID) - mean*mean;
    float rstd = rsqrtf(var + 1e-5f);
    #pragma unroll
    for (int nt = 0; nt < 4; ++nt){
      int jcol = (wn*4 + nt)*16 + c16;
      x[(row0 + m)*HID + jcol] = (vals[nt][r]-mean)*rstd*g1[jcol] + be1[jcol];
    }
  }
}

// FFN via split-bf16 MFMA (hi/lo, 3-term): fp32-accurate. (proven)
__global__ __launch_bounds__(256) void ffn_mfma2_k(
    const float* __restrict__ x,
    const unsigned short* __restrict__ W1h, const unsigned short* __restrict__ W1l,
    const float* __restrict__ b1,
    const unsigned short* __restrict__ W2h, const unsigned short* __restrict__ W2l,
    const float* __restrict__ b2, const float* __restrict__ gam,
    const float* __restrict__ bet, float* __restrict__ xout)
{
  __shared__ unsigned short Xh[32*128];
  __shared__ unsigned short Xl[32*128];
  __shared__ unsigned short Hh[32*512];
  __shared__ unsigned short Hl[32*512];
  __shared__ float red_s[2][2][16];
  __shared__ float red_q[2][2][16];
  int t = threadIdx.x;
  int wave = t >> 6, lane = t & 63;
  int g = lane >> 4, c16 = lane & 15;
  int wrh = wave >> 1;
  int wn  = wave & 1;
  size_t row0 = (size_t)blockIdx.x * 32;

  #pragma unroll
  for (int it = 0; it < 2; ++it){
    int idx8 = it*256 + t;
    int r = idx8 >> 4;
    int c8 = idx8 & 15;
    const float* src = x + (row0 + r)*HID + c8*8;
    float4 v0 = *(const float4*)(src);
    float4 v1 = *(const float4*)(src + 4);
    float f[8] = {v0.x,v0.y,v0.z,v0.w,v1.x,v1.y,v1.z,v1.w};
    s16x8 ph, pl;
    #pragma unroll
    for (int e = 0; e < 8; ++e){
      unsigned short hi = f2b(f[e]);
      ph[e] = (short)hi;
      pl[e] = (short)f2b(f[e] - b2f(hi));
    }
    int slot = c8 ^ (r & 15);
    *(s16x8*)((char*)Xh + r*256 + slot*16) = ph;
    *(s16x8*)((char*)Xl + r*256 + slot*16) = pl;
  }
  __syncthreads();

  int rloc = wrh*16 + c16;
  s16x8 afh[4], afl[4];
  #pragma unroll
  for (int kt = 0; kt < 4; ++kt){
    int slot = (kt*4 + g) ^ (rloc & 15);
    afh[kt] = *(const s16x8*)((const char*)Xh + rloc*256 + slot*16);
    afl[kt] = *(const s16x8*)((const char*)Xl + rloc*256 + slot*16);
  }

  for (int nt = 0; nt < 16; ++nt){
    int ntg = wn*16 + nt;
    int nrow = ntg*16 + c16;
    const unsigned short* wrh_p = W1h + nrow*HID + g*8;
    const unsigned short* wrl_p = W1l + nrow*HID + g*8;
    f32x4 acc = {0.f,0.f,0.f,0.f};
    #pragma unroll
    for (int kt = 0; kt < 4; ++kt){
      s16x8 bh = *(const s16x8*)(wrh_p + kt*32);
      s16x8 bl = *(const s16x8*)(wrl_p + kt*32);
      acc = __builtin_amdgcn_mfma_f32_16x16x32_bf16(afh[kt], bh, acc, 0,0,0);
      acc = __builtin_amdgcn_mfma_f32_16x16x32_bf16(afh[kt], bl, acc, 0,0,0);
      acc = __builtin_amdgcn_mfma_f32_16x16x32_bf16(afl[kt], bh, acc, 0,0,0);
    }
    float bv = b1[nrow];
    #pragma unroll
    for (int r = 0; r < 4; ++r){
      int m = wrh*16 + g*4 + r;
      float h = fmaxf(acc[r] + bv, 0.f);
      unsigned short hh = f2b(h);
      unsigned short hl = f2b(h - b2f(hh));
      int colb = nrow*2;
      int byteoff = m*1024 + (((((colb>>4) ^ (m & 15))<<4)) | (colb & 15));
      *(unsigned short*)((char*)Hh + byteoff) = hh;
      *(unsigned short*)((char*)Hl + byteoff) = hl;
    }
  }
  __syncthreads();

  f32x4 acc2[4];
  #pragma unroll
  for (int i = 0; i < 4; ++i) acc2[i] = (f32x4){0.f,0.f,0.f,0.f};
  int hrow = wrh*16 + c16;
  for (int kt2 = 0; kt2 < 16; ++kt2){
    int slot = (kt2*4 + g) ^ (hrow & 15);
    s16x8 hfh = *(const s16x8*)((const char*)Hh + hrow*1024 + slot*16);
    s16x8 hfl = *(const s16x8*)((const char*)Hl + hrow*1024 + slot*16);
    #pragma unroll
    for (int nt2 = 0; nt2 < 4; ++nt2){
      int jrow = (wn*4 + nt2)*16 + c16;
      s16x8 wfh = *(const s16x8*)(W2h + (size_t)jrow*INNER + kt2*32 + g*8);
      s16x8 wfl = *(const s16x8*)(W2l + (size_t)jrow*INNER + kt2*32 + g*8);
      acc2[nt2] = __builtin_amdgcn_mfma_f32_16x16x32_bf16(wfh, hfh, acc2[nt2], 0,0,0);
      acc2[nt2] = __builtin_amdgcn_mfma_f32_16x16x32_bf16(wfh, hfl, acc2[nt2], 0,0,0);
      acc2[nt2] = __builtin_amdgcn_mfma_f32_16x16x32_bf16(wfl, hfh, acc2[nt2], 0,0,0);
    }
  }

  size_t grow = row0 + (size_t)hrow;
  const float* xr = x + grow*HID;
  float vals[16];
  float s = 0.f, q = 0.f;
  #pragma unroll
  for (int nt2 = 0; nt2 < 4; ++nt2){
    #pragma unroll
    for (int r = 0; r < 4; ++r){
      int j = (wn*4 + nt2)*16 + g*4 + r;
      float v = acc2[nt2][r] + b2[j] + xr[j];
      vals[nt2*4+r] = v;
      s += v; q += v*v;
    }
  }
  s += __shfl_xor(s, 16, 64);
  s += __shfl_xor(s, 32, 64);
  q += __shfl_xor(q, 16, 64);
  q += __shfl_xor(q, 32, 64);
  if (g == 0){
    red_s[wrh][wn][c16] = s;
    red_q[wrh][wn][c16] = q;
  }
  __syncthreads();
  float s_tot = red_s[wrh][0][c16] + red_s[wrh][1][c16];
  float q_tot = red_q[wrh][0][c16] + red_q[wrh][1][c16];
  float mean = s_tot * (1.f/HID);
  float var = q_tot * (1.f/HID) - mean*mean;
  float rstd = rsqrtf(var + 1e-5f);
  float* orow = xout + grow*HID;
  #pragma unroll
  for (int nt2 = 0; nt2 < 4; ++nt2){
    #pragma unroll
    for (int r = 0; r < 4; ++r){
      int j = (wn*4 + nt2)*16 + g*4 + r;
      orow[j] = (vals[nt2*4+r]-mean)*rstd*gam[j] + bet[j];
    }
  }
}

// attention pooling + session vector. One block (128 thr) per batch elem.
__global__ void final_k(const float* __restrict__ x, const float* __restrict__ attW,
                        const float* __restrict__ attb, const float* __restrict__ sessW,
                        const float* __restrict__ sessb, float* __restrict__ sess){
  int b = blockIdx.x; int t = threadIdx.x;
  __shared__ float av[SEQ];
  __shared__ __align__(16) float cat[256];
  const float* xb = x + (size_t)b*SEQ*HID;
  if (t < SEQ){
    float a = attb[0];
    for (int c = 0; c < HID; ++c) a += xb[t*HID + c]*attW[c];
    av[t] = a;
  }
  __syncthreads();
  if (t == 0){
    float s = 0.f;
    for (int l = 0; l < SEQ; ++l) s += av[l];
    float inv = 1.f/s;
    for (int l = 0; l < SEQ; ++l) av[l] *= inv;
  }
  __syncthreads();
  float gacc = 0.f;
  for (int l = 0; l < SEQ; ++l) gacc += xb[l*HID + t]*av[l];
  cat[t] = xb[49*HID + t];
  cat[128+t] = gacc;
  __syncthreads();
  float acc = sessb[t];
  const float4* w = (const float4*)(sessW + (size_t)t*256);
  const float4* c4 = (const float4*)cat;
  #pragma unroll 8
  for (int j = 0; j < 64; ++j){
    float4 wv=w[j]; float4 cv=c4[j];
    acc += wv.x*cv.x + wv.y*cv.y + wv.z*cv.z + wv.w*cv.w;
  }
  sess[(size_t)b*HID + t] = acc;
}

// logits via MFMA hi/lo: 32 rows x 128 cols per block.
// grid.x = 64 row-tiles (fast-varying -> same n-slab adjacent for L2 emb reuse),
// grid.y = 391 n-slabs.
__global__ __launch_bounds__(256) void logits_mfma_k(
    const unsigned short* __restrict__ sessH, const unsigned short* __restrict__ sessL,
    const unsigned short* __restrict__ embH, const unsigned short* __restrict__ embL,
    float* __restrict__ out)
{
  __shared__ unsigned short Sh[32*128];
  __shared__ unsigned short Sl[32*128];
  int t = threadIdx.x;
  int wave = t >> 6, lane = t & 63;
  int g = lane >> 4, c16 = lane & 15;
  int wrh = wave >> 1;
  int wn  = wave & 1;
  size_t row0 = (size_t)blockIdx.x * 32;
  int n0 = blockIdx.y * 128;

  #pragma unroll
  for (int it = 0; it < 2; ++it){
    int idx8 = it*256 + t;
    int r = idx8 >> 4;
    int c8 = idx8 & 15;
    s16x8 ph = *(const s16x8*)(sessH + (row0 + r)*HID + c8*8);
    s16x8 pl = *(const s16x8*)(sessL + (row0 + r)*HID + c8*8);
    int slot = c8 ^ (r & 15);
    *(s16x8*)((char*)Sh + r*256 + slot*16) = ph;
    *(s16x8*)((char*)Sl + r*256 + slot*16) = pl;
  }
  __syncthreads();

  int rloc = wrh*16 + c16;
  s16x8 afh[4], afl[4];
  #pragma unroll
  for (int kt = 0; kt < 4; ++kt){
    int slot = (kt*4 + g) ^ (rloc & 15);
    afh[kt] = *(const s16x8*)((const char*)Sh + rloc*256 + slot*16);
    afl[kt] = *(const s16x8*)((const char*)Sl + rloc*256 + slot*16);
  }

  #pragma unroll
  for (int nt = 0; nt < 4; ++nt){
    int ncol = n0 + (wn*4 + nt)*16 + c16;    // < NPAD always
    const unsigned short* eh = embH + (size_t)ncol*HID + g*8;
    const unsigned short* el = embL + (size_t)ncol*HID + g*8;
    f32x4 acc = {0.f,0.f,0.f,0.f};
    #pragma unroll
    for (int kt = 0; kt < 4; ++kt){
      s16x8 bh = *(const s16x8*)(eh + kt*32);
      s16x8 bl = *(const s16x8*)(el + kt*32);
      acc = __builtin_amdgcn_mfma_f32_16x16x32_bf16(afh[kt], bh, acc, 0,0,0);
      acc = __builtin_amdgcn_mfma_f32_16x16x32_bf16(afh[kt], bl, acc, 0,0,0);
      acc = __builtin_amdgcn_mfma_f32_16x16x32_bf16(afl[kt], bh, acc, 0,0,0);
    }
    if (ncol < NOUT){
      #pragma unroll
      for (int r = 0; r < 4; ++r){
        int m = wrh*16 + g*4 + r;
        out[(row0 + m)*(size_t)NOUT + ncol] = acc[r];
      }
    }
  }
}

extern "C" void kernel_launch(void* const* d_in, const int* in_sizes, int n_in,
                              void* d_out, int out_size, void* d_ws, size_t ws_size,
                              hipStream_t stream){
  const int*   ids  = (const int*)d_in[0];
  const float* A    = (const float*)d_in[1];
  const float* emb  = (const float*)d_in[2];
  const float* pos  = (const float*)d_in[3];
  const float* mixW = (const float*)d_in[4];
  const float* mixb = (const float*)d_in[5];
  const float* Wq   = (const float*)d_in[6];
  const float* bq   = (const float*)d_in[7];
  const float* Wk   = (const float*)d_in[8];
  const float* bk   = (const float*)d_in[9];
  const float* Wv   = (const float*)d_in[10];
  const float* bv   = (const float*)d_in[11];
  const float* Wo   = (const float*)d_in[12];
  const float* bo   = (const float*)d_in[13];
  const float* ln1g = (const float*)d_in[14];
  const float* ln1b = (const float*)d_in[15];
  const float* W1   = (const float*)d_in[16];
  const float* b1   = (const float*)d_in[17];
  const float* W2   = (const float*)d_in[18];
  const float* b2   = (const float*)d_in[19];
  const float* ln2g = (const float*)d_in[20];
  const float* ln2b = (const float*)d_in[21];
  const float* attW = (const float*)d_in[22];
  const float* attb = (const float*)d_in[23];
  const float* sessW= (const float*)d_in[24];
  const float* sessb= (const float*)d_in[25];
  float* out = (float*)d_out;

  float* xA   = (float*)d_ws;
  float* xB   = xA + (size_t)BSZ*SEQ*HID;
  float* sess = xB + (size_t)BSZ*SEQ*HID;
  // FFN hi/lo splits in the sess region (1MB; sess written only by final_k).
  unsigned short* W1h = (unsigned short*)sess;
  unsigned short* W1l = W1h + (size_t)2*INNER*HID;
  unsigned short* W2h = W1l + (size_t)2*INNER*HID;
  unsigned short* W2l = W2h + (size_t)2*INNER*HID;
  // Weight splits in d_out tail; qkv/o scratch at d_out head.
  // All of d_out is overwritten by logits_mfma_k at the end.
  unsigned short* awb = (unsigned short*)(out + (size_t)out_size - 131072);
  unsigned short* Wqkvh = awb;
  unsigned short* Wqkvl = awb + 98304;
  unsigned short* Woh   = awb + 196608;
  unsigned short* Wol   = awb + 229376;
  unsigned short* mwb = (unsigned short*)(out + (size_t)out_size - 131072 - 65536);
  unsigned short* mWh = mwb;              // [2][128][256]
  unsigned short* mWl = mwb + 65536;
  float* qkvbuf = out;                               // 102400*384 floats
  float* obuf   = out + (size_t)102400*384;          // 102400*128 floats
  // logits hi/lo splits live in xB (dead after layer-1 mix; cvt runs after final_k)
  unsigned short* embHs = (unsigned short*)xB;
  unsigned short* embLs = embHs + (size_t)NPAD*HID;
  unsigned short* sessH = embLs + (size_t)NPAD*HID;
  unsigned short* sessL = sessH + (size_t)BSZ*HID;

  cvtw2_k<<<512, 256, 0, stream>>>(W1, W2, W1h, W1l, W2h, W2l);
  cvtw_qkvo_k<<<128, 256, 0, stream>>>(Wq, Wk, Wv, Wo, awb);
  cvtmix_k<<<256, 256, 0, stream>>>(mixW, mWh, mWl);
  embed_k<<<BSZ*SEQ, HID, 0, stream>>>(ids, emb, pos, xA);
  float* xc = xA; float* xn = xB;
  for (int i = 0; i < 2; ++i){
    mix_mfma_k<<<BSZ, 256, 0, stream>>>(A, xc,
        mWh + (size_t)i*HID*256, mWl + (size_t)i*HID*256, mixb + i*HID, xn);
    qkv_mfma_k<<<BSZ*SEQ/32, 256, 0, stream>>>(xn,
        Wqkvh + (size_t)i*384*HID, Wqkvl + (size_t)i*384*HID,
        bq + i*HID, bk + i*HID, bv + i*HID, qkvbuf);
    attn_core_k<<<BSZ*NHEAD, 256, 0, stream>>>(qkvbuf, obuf);
    oproj_mfma_k<<<BSZ*SEQ/32, 256, 0, stream>>>(obuf,
        Woh + (size_t)i*HID*HID, Wol + (size_t)i*HID*HID,
        bo + i*HID, ln1g + i*HID, ln1b + i*HID, xn);
    ffn_mfma2_k<<<BSZ*SEQ/32, 256, 0, stream>>>(xn,
        W1h + (size_t)i*INNER*HID, W1l + (size_t)i*INNER*HID, b1 + i*INNER,
        W2h + (size_t)i*INNER*HID, W2l + (size_t)i*INNER*HID, b2 + i*HID,
        ln2g + i*HID, ln2b + i*HID, xn);
    float* tmp = xc; xc = xn; xn = tmp;
  }
  final_k<<<BSZ, HID, 0, stream>>>(xc, attW, attb, sessW, sessb, sess);
  cvt_logits_k<<<NPAD*HID/256, 256, 0, stream>>>(sess, emb, sessH, sessL, embHs, embLs);
  dim3 lgrid(BSZ/32, NPAD/128);
  logits_mfma_k<<<lgrid, 256, 0, stream>>>(sessH, sessL, embHs, embLs, out);
}